// Round 14
// baseline (438.322 us; speedup 1.0000x reference)
//
#include <hip/hip_runtime.h>

#define BB 8
#define CP 21
#define CF 22
#define CLOW 3
#define CHIGH 256
#define WW 80
#define VV 6400
#define EVERT 6320
#define EE 12640
#define TT 16
#define SIGMA_F 0.002f
#define ROOT 3240          // grid center: seed for diameter search

#define NE (VV - 1)        // tree edges
#define NA (2 * NE)        // Euler arcs = 12798
#define NILA 0xFFFFu

__device__ __forceinline__ void edge_uv(int e, int& u, int& v) {
  if (e < EVERT) { u = e; v = e + WW; }
  else { int e2 = e - EVERT; int r = e2 / (WW - 1); int c = e2 - r * (WW - 1); u = r * WW + c; v = u + 1; }
}

// ---------------- K1: softmax over 21 channels, per pixel ----------------
__global__ void k_softmax(const float* __restrict__ preds, float* __restrict__ prob) {
  int i = blockIdx.x * blockDim.x + threadIdx.x;
  if (i >= BB * VV) return;
  int b = i / VV, v = i - b * VV;
  const float* p = preds + (size_t)b * CP * VV + v;
  float m = -1e30f;
  #pragma unroll
  for (int c = 0; c < CP; c++) m = fmaxf(m, p[c * VV]);
  float e[CP], s = 0.f;
  #pragma unroll
  for (int c = 0; c < CP; c++) { float x = expf(p[c * VV] - m); e[c] = x; s += x; }
  float inv = 1.f / s;
  float* o = prob + (size_t)b * CP * VV + v;
  #pragma unroll
  for (int c = 0; c < CP; c++) o[c * VV] = e[c] * inv;
}

// ---------------- K2: edge keys (float64 cost, top-50-bits | edge idx) ----------------
__global__ void k_edgekey(const float* __restrict__ low, const float* __restrict__ high,
                          unsigned long long* __restrict__ ekey) {
  int i = blockIdx.x * blockDim.x + threadIdx.x;
  if (i >= TT * EE) return;
  int t = i / EE, e = i - t * EE;
  int u, v; edge_uv(e, u, v);
  double acc = 0.0;
  if (t < BB) {
    const float* emb = low + (size_t)t * CLOW * VV;
    for (int c = 0; c < CLOW; c++) { double d = (double)emb[c * VV + u] - (double)emb[c * VV + v]; acc += d * d; }
  } else {
    const float* emb = high + (size_t)(t - BB) * CHIGH * VV;
    for (int c = 0; c < CHIGH; c++) { double d = (double)emb[c * VV + u] - (double)emb[c * VV + v]; acc += d * d; }
  }
  unsigned long long bits = (unsigned long long)__double_as_longlong(acc);
  ekey[i] = (bits & ~0x3FFFULL) | (unsigned long long)e;
}

// ---------------- K3: parallel Boruvka MST, edge compaction + barrier-free compression ----------------
__global__ __launch_bounds__(1024) void k_boruvka(const unsigned long long* __restrict__ ekey,
    int* __restrict__ mstU, int* __restrict__ mstV) {
  int t = blockIdx.x;
  const unsigned long long* key = ekey + (size_t)t * EE;
  int* mu = mstU + t * VV;
  int* mv = mstV + t * VV;
  __shared__ int comp[VV];
  __shared__ unsigned long long bst[VV];
  __shared__ unsigned short tgtS[VV];
  __shared__ unsigned short el0[EE];
  __shared__ unsigned short el1[EE];
  __shared__ int changed, cnt, necnt;
  int tid = threadIdx.x;
  const int nt = 1024;
  for (int v = tid; v < VV; v += nt) comp[v] = v;
  for (int e = tid; e < EE; e += nt) el0[e] = (unsigned short)e;
  if (tid == 0) cnt = 0;
  __syncthreads();
  unsigned short* els = el0;
  unsigned short* eld = el1;
  int ecnt = EE;
  for (int round = 0; round < 48 && ecnt > 0; round++) {
    for (int v = tid; v < VV; v += nt) bst[v] = ~0ULL;
    if (tid == 0) { changed = 0; necnt = 0; }
    __syncthreads();
    for (int j = tid; j < ecnt; j += nt) {
      int e = els[j];
      int u, v; edge_uv(e, u, v);
      int cu = comp[u], cv = comp[v];
      if (cu != cv) { unsigned long long k = key[e]; atomicMin(&bst[cu], k); atomicMin(&bst[cv], k); }
    }
    __syncthreads();
    for (int c = tid; c < VV; c += nt) {
      unsigned short tg = (unsigned short)NILA;
      if (comp[c] == c) {
        unsigned long long k = bst[c];
        if (k != ~0ULL) {
          int e = (int)(k & 0x3FFFULL);
          int u, v; edge_uv(e, u, v);
          int cu = comp[u], cv = comp[v];
          tg = (unsigned short)((cu == c) ? cv : cu);
        }
      }
      tgtS[c] = tg;
    }
    __syncthreads();
    for (int c = tid; c < VV; c += nt) {
      int o = tgtS[c];
      if (o == (int)NILA) continue;
      unsigned long long k = bst[c];
      if (bst[o] == k && c < o) continue;  // mutual minimum edge: smaller id stays root
      comp[c] = o;
      int slot = atomicAdd(&cnt, 1);
      int e = (int)(k & 0x3FFFULL);
      int u, v; edge_uv(e, u, v);
      mu[slot] = u; mv[slot] = v;
      changed = 1;
    }
    __syncthreads();
    if (!changed) break;
    // barrier-free full path compression
    for (int v = tid; v < VV; v += nt) {
      int c = comp[v];
      int c2 = comp[c];
      if (c2 != c) {
        int r0 = c2;
        while (true) { int n = comp[r0]; if (n == r0) break; r0 = n; }
        comp[v] = r0;
      }
    }
    __syncthreads();
    for (int j = tid; j < ecnt; j += nt) {
      int e = els[j];
      int u, v; edge_uv(e, u, v);
      if (comp[u] != comp[v]) { int s = atomicAdd(&necnt, 1); eld[s] = (unsigned short)e; }
    }
    __syncthreads();
    ecnt = necnt;
    __syncthreads();
    unsigned short* tp = els; els = eld; eld = tp;
  }
}

// ---------------- K4: Euler-tour rooting at the TRUE TREE CENTER ----------------
// List ranking once; re-rooting = rotation of arc positions. Double-BFS via rotated
// passes finds diameter endpoints (u,w) and center c; final pass emits parents/depths.
__global__ __launch_bounds__(1024) void k_buildtree(const int* __restrict__ mstU, const int* __restrict__ mstV,
    int* __restrict__ ordG, int* __restrict__ spG, int* __restrict__ pvG,
    int* __restrict__ lpG, int* __restrict__ nlevG) {
  int t = blockIdx.x;
  const int* mu = mstU + t * VV;
  const int* mv = mstV + t * VV;
  int tid = threadIdx.x;
  const int nt = 1024;

  __shared__ int buf4[32004];            // 128016-byte phase-overlapped arena
  char* buf = (char*)buf4;
  __shared__ int part[1024];
  __shared__ int lasts, smaxd, scenter;

  int* deg = (int*)(buf + 0);
  int* off = (int*)(buf + 25600);                          // alive through all passes
  unsigned short* adjA = (unsigned short*)(buf + 51208);   // alive through all passes
  unsigned short* succ = (unsigned short*)(buf + 76808);
  unsigned short* r_a = (unsigned short*)(buf + 0);        // ranking result (14 rounds even)
  unsigned short* r_b = (unsigned short*)(buf + 25604);
  unsigned short* nx_b = (unsigned short*)(buf + 102408);
  short* tv = (short*)(buf + 25604);                       // rotated tour values (r_b dead)
  unsigned short* parentS = (unsigned short*)(buf + 76808);// succ dead after ranking
  unsigned short* depthS  = (unsigned short*)(buf + 89608);
  unsigned short* dW      = (unsigned short*)(buf + 102408); // nx_b dead after ranking
  int* lev = (int*)(buf + 0);                              // Phase D (r_a dead)
  int* cur = (int*)(buf + 25604);                          // Phase D (tv dead; off dead)
  unsigned short* ordS = (unsigned short*)(buf + 102408);  // Phase D (dW dead)
  unsigned short* posS = (unsigned short*)(buf + 115208);

  // ---- Phase A: CSR + Euler successors ----
  for (int v = tid; v < VV; v += nt) deg[v] = 0;
  __syncthreads();
  for (int e = tid; e < NE; e += nt) { atomicAdd(&deg[mu[e]], 1); atomicAdd(&deg[mv[e]], 1); }
  __syncthreads();
  {
    const int SCH = 7;
    int base = tid * SCH;
    int s = 0;
    #pragma unroll
    for (int k = 0; k < SCH; k++) { int v = base + k; if (v < VV) s += deg[v]; }
    part[tid] = s;
    __syncthreads();
    for (int d = 1; d < 1024; d <<= 1) {
      int add = (tid >= d) ? part[tid - d] : 0;
      __syncthreads();
      part[tid] += add;
      __syncthreads();
    }
    int ex = part[tid] - s;
    #pragma unroll
    for (int k = 0; k < SCH; k++) { int v = base + k; if (v < VV) { off[v] = ex; ex += deg[v]; } }
    if (tid == 1023) off[VV] = ex;
  }
  __syncthreads();
  for (int v = tid; v < VV; v += nt) deg[v] = off[v];   // cursors
  __syncthreads();
  for (int e = tid; e < NE; e += nt) {
    int u = mu[e], v = mv[e];
    adjA[atomicAdd(&deg[u], 1)] = (unsigned short)(2 * e);
    adjA[atomicAdd(&deg[v], 1)] = (unsigned short)(2 * e + 1);
  }
  __syncthreads();
  for (int v = tid; v < VV; v += nt) {
    int b0 = off[v], dv = off[v + 1] - b0;
    for (int k = 0; k < dv; k++) {
      unsigned short a = adjA[b0 + k];
      unsigned short b = adjA[b0 + ((k + 1 == dv) ? 0 : k + 1)];
      succ[a ^ 1] = b;
    }
  }
  if (tid == 0) {
    lasts = adjA[off[ROOT] + (off[ROOT + 1] - off[ROOT]) - 1] ^ 1;
  }
  __syncthreads();
  if (tid == 0) succ[lasts] = (unsigned short)NILA;
  __syncthreads();
  // ---- Phase B: list ranking (r = #arcs strictly after; cycle broken at ROOT) ----
  for (int a = tid; a < NA; a += nt) r_a[a] = (succ[a] == (unsigned short)NILA) ? 0 : 1;
  __syncthreads();
  {
    unsigned short *rx = r_a, *ry = r_b, *nxp = succ, *nyp = nx_b;
    for (int rd = 0; rd < 14; rd++) {
      for (int a = tid; a < NA; a += nt) {
        unsigned short n = nxp[a];
        if (n == (unsigned short)NILA) { ry[a] = rx[a]; nyp[a] = (unsigned short)NILA; }
        else { ry[a] = rx[a] + rx[n]; nyp[a] = nxp[n]; }
      }
      __syncthreads();
      unsigned short* tp;
      tp = rx; rx = ry; ry = tp;
      tp = nxp; nxp = nyp; nyp = tp;
    }
  }
  __syncthreads();
  // ---- rooted pass (rotation of the Euler cycle); returns packed (maxdepth<<13)|argmax ----
  auto pass = [&](int rootv, unsigned short* dOut, bool wPar) -> int {
    if (tid == 0) smaxd = 0;
    int a0 = adjA[off[rootv]];                      // an outgoing arc of rootv
    int shift = NA - 1 - (int)r_a[a0];
    __syncthreads();
    for (int a = tid; a < NA; a += nt) {
      int pa = NA - 1 - (int)r_a[a] - shift; if (pa < 0) pa += NA;
      int pb = NA - 1 - (int)r_a[a ^ 1] - shift; if (pb < 0) pb += NA;
      tv[pa] = (pa < pb) ? (short)1 : (short)-1;
    }
    __syncthreads();
    {
      const int SCH = 13;
      int base = tid * SCH;
      int lim = base + SCH; if (lim > NA) lim = NA;
      int s = 0;
      for (int j = base; j < lim; j++) s += tv[j];
      part[tid] = s;
      __syncthreads();
      for (int d = 1; d < 1024; d <<= 1) {
        int add = (tid >= d) ? part[tid - d] : 0;
        __syncthreads();
        part[tid] += add;
        __syncthreads();
      }
      int run = part[tid] - s;
      for (int j = base; j < lim; j++) { run += tv[j]; tv[j] = (short)run; }
    }
    __syncthreads();
    for (int a = tid; a < NA; a += nt) {
      int pa = NA - 1 - (int)r_a[a] - shift; if (pa < 0) pa += NA;
      int pb = NA - 1 - (int)r_a[a ^ 1] - shift; if (pb < 0) pb += NA;
      if (pa < pb) {   // down arc: tail -> head = parent -> child
        int e = a >> 1;
        int u0 = mu[e], v0 = mv[e];
        int head = (a & 1) ? u0 : v0;
        int tail = (a & 1) ? v0 : u0;
        int d = (int)tv[pa];
        dOut[head] = (unsigned short)d;
        if (wPar) parentS[head] = (unsigned short)tail;
        atomicMax(&smaxd, (d << 13) | head);
      }
    }
    if (tid == 0) { dOut[rootv] = 0; if (wPar) parentS[rootv] = (unsigned short)rootv; }
    __syncthreads();
    int ret = smaxd;
    __syncthreads();
    return ret;
  };
  // double-BFS center finding
  int pk1 = pass(ROOT, depthS, false);
  int u = pk1 & 0x1FFF;
  int pk2 = pass(u, depthS, false);          // depth_u
  int D = pk2 >> 13;
  int w = pk2 & 0x1FFF;
  int pk3 = pass(w, dW, false);              // depth_w
  (void)pk3;
  if (tid == 0) scenter = 0x7FFFFFFF;
  __syncthreads();
  {
    int half = D >> 1;
    for (int v = tid; v < VV; v += nt) {
      if ((int)depthS[v] + (int)dW[v] == D && (int)depthS[v] == half) atomicMin(&scenter, v);
    }
  }
  __syncthreads();
  int cvert = (scenter == 0x7FFFFFFF) ? ROOT : scenter;
  int pk4 = pass(cvert, depthS, true);       // final parents + depths
  int maxd = pk4 >> 13;
  // ---- Phase D: counting sort by depth ----
  for (int d = tid; d <= VV; d += nt) lev[d] = 0;
  __syncthreads();
  for (int v = tid; v < VV; v += nt) atomicAdd(&lev[depthS[v]], 1);
  __syncthreads();
  {
    const int SCH = 7;
    int base = tid * SCH;
    int s = 0;
    #pragma unroll
    for (int k = 0; k < SCH; k++) { int d = base + k; if (d <= VV) s += lev[d]; }
    part[tid] = s;
    __syncthreads();
    for (int d = 1; d < 1024; d <<= 1) {
      int add = (tid >= d) ? part[tid - d] : 0;
      __syncthreads();
      part[tid] += add;
      __syncthreads();
    }
    int ex = part[tid] - s;
    #pragma unroll
    for (int k = 0; k < SCH; k++) {
      int d = base + k;
      if (d <= VV) {
        int st = ex;
        ex += lev[d];
        if (d < VV) cur[d] = st;
        lpG[t * (VV + 1) + d] = st;
      }
    }
  }
  __syncthreads();
  for (int v = tid; v < VV; v += nt) {
    int d = depthS[v];
    int slot = atomicAdd(&cur[d], 1);
    ordS[slot] = (unsigned short)v;
    posS[v] = (unsigned short)slot;
  }
  __syncthreads();
  for (int j = tid; j < VV; j += nt) {
    int v = ordS[j];
    int pv = parentS[v];
    ordG[t * VV + j] = v;
    pvG[t * VV + j] = pv;
    spG[t * VV + j] = posS[pv];
  }
  if (tid == 0) nlevG[t] = maxd + 1;
}

// ---------------- K5: per-position weight to parent (edge-key reuse; root -> 1, unused) ----------------
__global__ void k_weights(const unsigned long long* __restrict__ ekey,
                          const int* __restrict__ ordG, const int* __restrict__ pvG,
                          float* __restrict__ wvp) {
  int i = blockIdx.x * blockDim.x + threadIdx.x;
  if (i >= TT * VV) return;
  int t = i / VV;
  int v = ordG[i], p = pvG[i];
  float wout;
  if (v == p) {
    wout = 1.0f;  // root (overridden in filter transform)
  } else {
    int a = v < p ? v : p;
    int diff = v < p ? p - v : v - p;
    int e;
    if (diff == WW) e = a;
    else { int r = a / WW, c = a - r * WW; e = EVERT + r * (WW - 1) + c; }
    unsigned long long k = ekey[(size_t)t * EE + e];
    double cost = __longlong_as_double((long long)(k & ~0x3FFFULL));
    wout = expf(-(float)cost / SIGMA_F);
  }
  wvp[i] = wout;
}

// ---------------- K6: tree filter — level-sweep up (wave 0), packed-float2 doubling down ----------------
// 512 threads: bulk phases at 8 waves; up-sweep chain on wave 0 only. (Round-12 verbatim.)
__global__ __launch_bounds__(512) void k_filter_pc(const float* __restrict__ Fsrc, float* __restrict__ Araw,
    const float* __restrict__ wvp, const int* __restrict__ ordG, const int* __restrict__ spG,
    const int* __restrict__ lpG, const int* __restrict__ nlevG, int treeBase) {
  int blk = blockIdx.x;
  int b = blk / CF, ch = blk - b * CF;
  int t = treeBase + b;
  // LDS arena: ab0 [0,51200) | ab1 [51200,102400) {aliases S,w} | sp0 | sp1 | lpS
  __shared__ alignas(16) char arena[140816];
  float2* ab0 = (float2*)(arena);
  float2* ab1 = (float2*)(arena + 51200);
  float*  S   = (float*)(arena + 51200);     // dead after affine transform
  float*  w   = (float*)(arena + 76800);     // dead after affine transform
  unsigned short* sp0 = (unsigned short*)(arena + 102400);
  unsigned short* sp1 = (unsigned short*)(arena + 115200);
  unsigned short* lpS = (unsigned short*)(arena + 128000);  // u16[VV+1]
  const int* ord = ordG + t * VV;
  const int* spt = spG + t * VV;
  const float* wsrc = wvp + t * VV;
  const int* lp = lpG + t * (VV + 1);
  int tid = threadIdx.x;
  const int nt = 512;
  int NL = nlevG[t];
  for (int j = tid; j <= NL; j += nt) lpS[j] = (unsigned short)lp[j];
  const bool norm_in = (treeBase != 0);
  for (int j = tid; j < VV; j += nt) {
    sp0[j] = (unsigned short)spt[j];
    w[j] = wsrc[j];
    float val;
    if (ch < CP) {
      int v = ord[j];
      if (!norm_in) val = Fsrc[((size_t)b * CP + ch) * VV + v];
      else          val = Fsrc[((size_t)b * CF + ch) * VV + v] / Fsrc[((size_t)b * CF + CP) * VV + v];
    } else val = 1.0f;
    S[j] = val;
  }
  __syncthreads();
  // ---- up-sweep: wave 0 only, barrier-free, level bounds carried/prefetched ----
  if (tid < 64) {
    int s1 = lpS[NL];
    int s0 = lpS[NL - 1];
    for (int l = NL - 1; l >= 1; l--) {
      int s0n = (l > 1) ? (int)lpS[l - 1] : 0;
      for (int j = s0 + tid; j < s1; j += 64) {
        atomicAdd(&S[sp0[j]], w[j] * S[j]);
      }
      asm volatile("s_waitcnt lgkmcnt(0)" ::: "memory");
      __builtin_amdgcn_sched_barrier(0);
      s1 = s0; s0 = s0n;
    }
  }
  __syncthreads();
  // ---- transform to packed affine: ab0[j] = (a,b); root (pos 0) = (0, S[0]) ----
  for (int j = tid; j < VV; j += nt) {
    float wv = w[j];
    float a = (j == 0) ? 0.f : wv;
    float bv = (j == 0) ? S[0] : S[j] * (1.f - wv * wv);
    ab0[j] = make_float2(a, bv);
  }
  __syncthreads();
  // ---- down-sweep: packed affine pointer doubling with converged-lane skip ----
  int rounds = 0;
  { int d = 1; while (d < NL) { d <<= 1; rounds++; } }
  float2 *abs_ = ab0, *abd_ = ab1;          // round 0 writes over dead S,w
  unsigned short *ps_ = sp0, *pd_ = sp1;
  for (int r = 0; r < rounds; r++) {
    for (int j = tid; j < VV; j += nt) {
      float2 m = abs_[j];
      int p = ps_[j];
      float2 o = m;
      int pn = p;
      if (m.x != 0.f) {                      // not yet converged: compose with parent map
        float2 mp = abs_[p];
        pn = ps_[p];
        o.x = m.x * mp.x;
        o.y = fmaf(m.x, mp.y, m.y);
      }
      abd_[j] = o;
      pd_[j] = (unsigned short)pn;
    }
    __syncthreads();
    float2* tf = abs_; abs_ = abd_; abd_ = tf;
    unsigned short* tu = ps_; ps_ = pd_; pd_ = tu;
  }
  // ---- scatter to vertex space ----
  float* Ob = Araw + ((size_t)b * CF + ch) * VV;
  for (int j = tid; j < VV; j += nt) Ob[ord[j]] = abs_[j].y;
}

// ---------------- K7: ROI-masked L1 loss (fused normalize of stage 2) ----------------
__global__ void k_loss(const float* __restrict__ prob, const float* __restrict__ Araw2,
                       const int* __restrict__ roi, double* __restrict__ acc) {
  int i = blockIdx.x * blockDim.x + threadIdx.x;
  int tid = threadIdx.x;
  double s = 0.0, n = 0.0;
  if (i < BB * VV) {
    int b = i / VV, v = i - b * VV;
    if (roi[i] != 0) {
      n = 1.0;
      const float* pb = prob + (size_t)b * CP * VV + v;
      const float* ab = Araw2 + (size_t)b * CF * VV + v;
      float inv = 1.0f / ab[CP * VV];
      float ls = 0.f;
      #pragma unroll
      for (int c = 0; c < CP; c++) ls += fabsf(pb[c * VV] - ab[c * VV] * inv);
      s = (double)ls;
    }
  }
  __shared__ double rs[256], rn[256];
  rs[tid] = s; rn[tid] = n;
  __syncthreads();
  for (int d = 128; d > 0; d >>= 1) {
    if (tid < d) { rs[tid] += rs[tid + d]; rn[tid] += rn[tid + d]; }
    __syncthreads();
  }
  if (tid == 0) { atomicAdd(&acc[0], rs[0]); atomicAdd(&acc[1], rn[0]); }
}

__global__ void k_finalize(const double* __restrict__ acc, float* __restrict__ out) {
  out[0] = (acc[1] > 0.0) ? (float)(acc[0] / acc[1]) : 0.0f;
}

extern "C" void kernel_launch(void* const* d_in, const int* in_sizes, int n_in,
                              void* d_out, int out_size, void* d_ws, size_t ws_size,
                              hipStream_t stream) {
  const float* preds = (const float*)d_in[0];
  const float* low   = (const float*)d_in[1];
  const float* high  = (const float*)d_in[2];
  const int*   roi   = (const int*)d_in[3];
  float* out = (float*)d_out;

  char* w = (char*)d_ws;
  size_t off = 0;
  auto alloc = [&](size_t bytes) -> void* {
    void* p = w + off;
    off += (bytes + 255) & ~(size_t)255;
    return p;
  };
  float* prob  = (float*)alloc((size_t)BB * CP * VV * 4);
  float* Araw1 = (float*)alloc((size_t)BB * CF * VV * 4);
  float* Araw2 = (float*)alloc((size_t)BB * CF * VV * 4);
  unsigned long long* ekey = (unsigned long long*)alloc((size_t)TT * EE * 8);
  int* mstU = (int*)alloc((size_t)TT * VV * 4);
  int* mstV = (int*)alloc((size_t)TT * VV * 4);
  int* ordG = (int*)alloc((size_t)TT * VV * 4);
  int* spG  = (int*)alloc((size_t)TT * VV * 4);
  int* pvG  = (int*)alloc((size_t)TT * VV * 4);
  int* lpG  = (int*)alloc((size_t)TT * (VV + 1) * 4);
  int* nlev = (int*)alloc((size_t)TT * 4);
  float* wvp = (float*)alloc((size_t)TT * VV * 4);
  double* acc = (double*)alloc(16);

  hipMemsetAsync(acc, 0, 16, stream);

  k_softmax<<<(BB * VV + 255) / 256, 256, 0, stream>>>(preds, prob);
  k_edgekey<<<(TT * EE + 255) / 256, 256, 0, stream>>>(low, high, ekey);
  k_boruvka<<<TT, 1024, 0, stream>>>(ekey, mstU, mstV);
  k_buildtree<<<TT, 1024, 0, stream>>>(mstU, mstV, ordG, spG, pvG, lpG, nlev);
  k_weights<<<(TT * VV + 255) / 256, 256, 0, stream>>>(ekey, ordG, pvG, wvp);
  k_filter_pc<<<BB * CF, 512, 0, stream>>>(prob,  Araw1, wvp, ordG, spG, lpG, nlev, 0);
  k_filter_pc<<<BB * CF, 512, 0, stream>>>(Araw1, Araw2, wvp, ordG, spG, lpG, nlev, BB);
  k_loss<<<(BB * VV + 255) / 256, 256, 0, stream>>>(prob, Araw2, roi, acc);
  k_finalize<<<1, 1, 0, stream>>>(acc, out);
}

// Round 16
// 377.713 us; speedup vs baseline: 1.1605x; 1.1605x over previous
//
#include <hip/hip_runtime.h>

#define BB 8
#define CP 21
#define CF 22
#define CLOW 3
#define CHIGH 256
#define WW 80
#define VV 6400
#define EVERT 6320
#define EE 12640
#define TT 16
#define SIGMA_F 0.002f
#define ROOT 3240          // seed vertex for tour break / diameter search

#define NE (VV - 1)        // tree edges
#define NA (2 * NE)        // Euler arcs = 12798
#define NILA 0xFFFFu
#define NB 200             // ceil(NA/64) RMQ blocks

__device__ __forceinline__ void edge_uv(int e, int& u, int& v) {
  if (e < EVERT) { u = e; v = e + WW; }
  else { int e2 = e - EVERT; int r = e2 / (WW - 1); int c = e2 - r * (WW - 1); u = r * WW + c; v = u + 1; }
}

// ---------------- K1: softmax over 21 channels, per pixel ----------------
__global__ void k_softmax(const float* __restrict__ preds, float* __restrict__ prob) {
  int i = blockIdx.x * blockDim.x + threadIdx.x;
  if (i >= BB * VV) return;
  int b = i / VV, v = i - b * VV;
  const float* p = preds + (size_t)b * CP * VV + v;
  float m = -1e30f;
  #pragma unroll
  for (int c = 0; c < CP; c++) m = fmaxf(m, p[c * VV]);
  float e[CP], s = 0.f;
  #pragma unroll
  for (int c = 0; c < CP; c++) { float x = expf(p[c * VV] - m); e[c] = x; s += x; }
  float inv = 1.f / s;
  float* o = prob + (size_t)b * CP * VV + v;
  #pragma unroll
  for (int c = 0; c < CP; c++) o[c * VV] = e[c] * inv;
}

// ---------------- K2: edge keys (float64 cost, top-50-bits | edge idx) ----------------
__global__ void k_edgekey(const float* __restrict__ low, const float* __restrict__ high,
                          unsigned long long* __restrict__ ekey) {
  int i = blockIdx.x * blockDim.x + threadIdx.x;
  if (i >= TT * EE) return;
  int t = i / EE, e = i - t * EE;
  int u, v; edge_uv(e, u, v);
  double acc = 0.0;
  if (t < BB) {
    const float* emb = low + (size_t)t * CLOW * VV;
    for (int c = 0; c < CLOW; c++) { double d = (double)emb[c * VV + u] - (double)emb[c * VV + v]; acc += d * d; }
  } else {
    const float* emb = high + (size_t)(t - BB) * CHIGH * VV;
    for (int c = 0; c < CHIGH; c++) { double d = (double)emb[c * VV + u] - (double)emb[c * VV + v]; acc += d * d; }
  }
  unsigned long long bits = (unsigned long long)__double_as_longlong(acc);
  ekey[i] = (bits & ~0x3FFFULL) | (unsigned long long)e;
}

// ---------------- K3: parallel Boruvka MST, edge compaction + barrier-free compression ----------------
__global__ __launch_bounds__(1024) void k_boruvka(const unsigned long long* __restrict__ ekey,
    int* __restrict__ mstU, int* __restrict__ mstV) {
  int t = blockIdx.x;
  const unsigned long long* key = ekey + (size_t)t * EE;
  int* mu = mstU + t * VV;
  int* mv = mstV + t * VV;
  __shared__ int comp[VV];
  __shared__ unsigned long long bst[VV];
  __shared__ unsigned short tgtS[VV];
  __shared__ unsigned short el0[EE];
  __shared__ unsigned short el1[EE];
  __shared__ int changed, cnt, necnt;
  int tid = threadIdx.x;
  const int nt = 1024;
  for (int v = tid; v < VV; v += nt) comp[v] = v;
  for (int e = tid; e < EE; e += nt) el0[e] = (unsigned short)e;
  if (tid == 0) cnt = 0;
  __syncthreads();
  unsigned short* els = el0;
  unsigned short* eld = el1;
  int ecnt = EE;
  for (int round = 0; round < 48 && ecnt > 0; round++) {
    for (int v = tid; v < VV; v += nt) bst[v] = ~0ULL;
    if (tid == 0) { changed = 0; necnt = 0; }
    __syncthreads();
    for (int j = tid; j < ecnt; j += nt) {
      int e = els[j];
      int u, v; edge_uv(e, u, v);
      int cu = comp[u], cv = comp[v];
      if (cu != cv) { unsigned long long k = key[e]; atomicMin(&bst[cu], k); atomicMin(&bst[cv], k); }
    }
    __syncthreads();
    for (int c = tid; c < VV; c += nt) {
      unsigned short tg = (unsigned short)NILA;
      if (comp[c] == c) {
        unsigned long long k = bst[c];
        if (k != ~0ULL) {
          int e = (int)(k & 0x3FFFULL);
          int u, v; edge_uv(e, u, v);
          int cu = comp[u], cv = comp[v];
          tg = (unsigned short)((cu == c) ? cv : cu);
        }
      }
      tgtS[c] = tg;
    }
    __syncthreads();
    for (int c = tid; c < VV; c += nt) {
      int o = tgtS[c];
      if (o == (int)NILA) continue;
      unsigned long long k = bst[c];
      if (bst[o] == k && c < o) continue;  // mutual minimum edge: smaller id stays root
      comp[c] = o;
      int slot = atomicAdd(&cnt, 1);
      int e = (int)(k & 0x3FFFULL);
      int u, v; edge_uv(e, u, v);
      mu[slot] = u; mv[slot] = v;
      changed = 1;
    }
    __syncthreads();
    if (!changed) break;
    // barrier-free full path compression
    for (int v = tid; v < VV; v += nt) {
      int c = comp[v];
      int c2 = comp[c];
      if (c2 != c) {
        int r0 = c2;
        while (true) { int n = comp[r0]; if (n == r0) break; r0 = n; }
        comp[v] = r0;
      }
    }
    __syncthreads();
    for (int j = tid; j < ecnt; j += nt) {
      int e = els[j];
      int u, v; edge_uv(e, u, v);
      if (comp[u] != comp[v]) { int s = atomicAdd(&necnt, 1); eld[s] = (unsigned short)e; }
    }
    __syncthreads();
    ecnt = necnt;
    __syncthreads();
    unsigned short* tp = els; els = eld; eld = tp;
  }
}

// ---------------- K4: Euler-tour rooting at the TRUE TREE CENTER, single scan + O(1) RMQ ----------------
// dist(x,y) = H[Kx-1] + H[Ky-1] - 2*min H[p], p in [minK-1, maxK-1] (H[-1]=0).
// distW/distC live in a DEDICATED buffer (round-15 bug: they aliased prefmin -> race -> NaN).
__global__ __launch_bounds__(1024) void k_buildtree(const int* __restrict__ mstU, const int* __restrict__ mstV,
    int* __restrict__ ordG, int* __restrict__ spG, int* __restrict__ pvG,
    int* __restrict__ lpG, int* __restrict__ nlevG) {
  int t = blockIdx.x;
  const int* mu = mstU + t * VV;
  const int* mv = mstV + t * VV;
  int tid = threadIdx.x;
  const int nt = 1024;

  __shared__ int buf4[32004];            // 128016-byte phase-overlapped arena
  char* buf = (char*)buf4;
  __shared__ int part[1024];
  __shared__ short tbl[8 * NB];
  __shared__ unsigned short dbuf2[VV];   // dedicated distW/distC (NO aliasing)
  __shared__ int lasts, spackU, spackW, scenter, smaxd;

  // Phase A regions
  int* deg = (int*)(buf + 0);
  int* off = (int*)(buf + 25600);
  unsigned short* adjA = (unsigned short*)(buf + 51208);
  unsigned short* succ = (unsigned short*)(buf + 76808);
  // Ranking scratch: rx @0 (deg dead), nxp @76808 (succ), ry @102408, nyp @25600 (off dead)
  unsigned short* r_a = (unsigned short*)(buf + 0);
  unsigned short* r_y = (unsigned short*)(buf + 102408);
  unsigned short* nx_y = (unsigned short*)(buf + 25600);
  // Tour profile + RMQ
  short* H = (short*)(buf + 51208);                        // adjA dead
  unsigned short* depthR = (unsigned short*)(buf + 76808); // succ dead
  unsigned short* firstK = (unsigned short*)(buf + 89608);
  short* prefmin = (short*)(buf + 102408);                 // r_y dead
  short* sufmin  = (short*)(buf + 25600);                  // nx_y dead
  unsigned short* distU = (unsigned short*)(buf + 76808);  // overwrites depthR (after u-select)
  unsigned short* parentS = (unsigned short*)(buf + 76808);// overwrites distU (after c-select)
  // Phase D
  int* lev = (int*)(buf + 25600);                          // sufmin dead
  int* cur = (int*)(buf + 51208);                          // H dead
  unsigned short* ordS = (unsigned short*)(buf + 89608);   // firstK dead
  unsigned short* posS = (unsigned short*)(buf + 102408);  // prefmin dead

  // ---- Phase A: CSR + Euler successors ----
  for (int v = tid; v < VV; v += nt) deg[v] = 0;
  __syncthreads();
  for (int e = tid; e < NE; e += nt) { atomicAdd(&deg[mu[e]], 1); atomicAdd(&deg[mv[e]], 1); }
  __syncthreads();
  {
    const int SCH = 7;
    int base = tid * SCH;
    int s = 0;
    #pragma unroll
    for (int k = 0; k < SCH; k++) { int v = base + k; if (v < VV) s += deg[v]; }
    part[tid] = s;
    __syncthreads();
    for (int d = 1; d < 1024; d <<= 1) {
      int add = (tid >= d) ? part[tid - d] : 0;
      __syncthreads();
      part[tid] += add;
      __syncthreads();
    }
    int ex = part[tid] - s;
    #pragma unroll
    for (int k = 0; k < SCH; k++) { int v = base + k; if (v < VV) { off[v] = ex; ex += deg[v]; } }
    if (tid == 1023) off[VV] = ex;
  }
  __syncthreads();
  for (int v = tid; v < VV; v += nt) deg[v] = off[v];   // cursors
  __syncthreads();
  for (int e = tid; e < NE; e += nt) {
    int u = mu[e], v = mv[e];
    adjA[atomicAdd(&deg[u], 1)] = (unsigned short)(2 * e);       // arc u->v (head = v)
    adjA[atomicAdd(&deg[v], 1)] = (unsigned short)(2 * e + 1);   // arc v->u (head = u)
  }
  __syncthreads();
  for (int v = tid; v < VV; v += nt) {
    int b0 = off[v], dv = off[v + 1] - b0;
    for (int k = 0; k < dv; k++) {
      unsigned short a = adjA[b0 + k];
      unsigned short b = adjA[b0 + ((k + 1 == dv) ? 0 : k + 1)];
      succ[a ^ 1] = b;
    }
  }
  if (tid == 0) lasts = adjA[off[ROOT] + (off[ROOT + 1] - off[ROOT]) - 1] ^ 1;
  __syncthreads();
  if (tid == 0) succ[lasts] = (unsigned short)NILA;
  __syncthreads();
  // ---- Phase B: list ranking (r = #arcs strictly after; off/adjA now dead) ----
  for (int a = tid; a < NA; a += nt) r_a[a] = (succ[a] == (unsigned short)NILA) ? 0 : 1;
  __syncthreads();
  {
    unsigned short *rx = r_a, *ry = r_y, *nxp = succ, *nyp = nx_y;
    for (int rd = 0; rd < 14; rd++) {
      for (int a = tid; a < NA; a += nt) {
        unsigned short n = nxp[a];
        if (n == (unsigned short)NILA) { ry[a] = rx[a]; nyp[a] = (unsigned short)NILA; }
        else { ry[a] = rx[a] + rx[n]; nyp[a] = nxp[n]; }
      }
      __syncthreads();
      unsigned short* tp;
      tp = rx; rx = ry; ry = tp;
      tp = nxp; nxp = nyp; nyp = tp;
    }
    // 14 rounds (even) -> ranks in r_a
  }
  // ---- tour values + single inclusive scan -> H ----
  for (int a = tid; a < NA; a += nt) {
    int pa = NA - 1 - (int)r_a[a];
    int pb = NA - 1 - (int)r_a[a ^ 1];
    H[pa] = (pa < pb) ? (short)1 : (short)-1;
  }
  __syncthreads();
  {
    const int SCH = 13;
    int base = tid * SCH;
    int lim = base + SCH; if (lim > NA) lim = NA;
    int s = 0;
    for (int j = base; j < lim; j++) s += H[j];
    part[tid] = s;
    __syncthreads();
    for (int d = 1; d < 1024; d <<= 1) {
      int add = (tid >= d) ? part[tid - d] : 0;
      __syncthreads();
      part[tid] += add;
      __syncthreads();
    }
    int run = part[tid] - s;
    for (int j = base; j < lim; j++) { run += H[j]; H[j] = (short)run; }
  }
  __syncthreads();
  // ---- extract original-root depths + entry steps K ----
  if (tid == 0) { spackU = 0; smaxd = 0; scenter = 0x7FFFFFFF; }
  __syncthreads();
  for (int a = tid; a < NA; a += nt) {
    int pa = NA - 1 - (int)r_a[a];
    int pb = NA - 1 - (int)r_a[a ^ 1];
    if (pa < pb) {                       // down arc under ROOT rooting
      int e = a >> 1;
      int head = (a & 1) ? mu[e] : mv[e];
      depthR[head] = (unsigned short)H[pa];
      firstK[head] = (unsigned short)(pa + 1);
    }
  }
  if (tid == 0) { depthR[ROOT] = 0; firstK[ROOT] = 0; }
  __syncthreads();
  for (int v = tid; v < VV; v += nt) atomicMax(&spackU, ((int)depthR[v] << 13) | v);
  __syncthreads();
  // ---- RMQ build: per-64-block prefix/suffix mins + sparse table over block mins ----
  if (tid < NB) {
    int s0 = tid * 64, e0 = s0 + 64; if (e0 > NA) e0 = NA;
    short m = 32767;
    for (int p = s0; p < e0; p++) { short h = H[p]; if (h < m) m = h; prefmin[p] = m; }
    m = 32767;
    for (int p = e0 - 1; p >= s0; p--) { short h = H[p]; if (h < m) m = h; sufmin[p] = m; }
    tbl[tid] = sufmin[s0];
  }
  __syncthreads();
  for (int k = 1; k < 8; k++) {
    short vv_ = 0;
    if (tid < NB) {
      int o = tid + (1 << (k - 1));
      short a = tbl[(k - 1) * NB + tid];
      short b2 = (o < NB) ? tbl[(k - 1) * NB + o] : (short)32767;
      vv_ = (a < b2) ? a : b2;
    }
    __syncthreads();
    if (tid < NB) tbl[k * NB + tid] = vv_;
    __syncthreads();
  }
  // O(1)-ish tree distance between entry-steps K1, K2
  auto distq = [&](int K1, int K2) -> int {
    if (K1 == K2) return 0;
    int l = (K1 < K2 ? K1 : K2) - 1;
    int r = (K1 > K2 ? K1 : K2) - 1;
    int m = 32767;
    int l0 = l < 0 ? 0 : l;
    int bl = l0 >> 6, br = r >> 6;
    if (bl == br) {
      for (int p = l0; p <= r; p++) { int h = H[p]; if (h < m) m = h; }
    } else {
      int a = sufmin[l0], b2 = prefmin[r];
      m = a < b2 ? a : b2;
      int lo = bl + 1, hi = br - 1;
      if (lo <= hi) {
        int L = hi - lo + 1;
        int k = 31 - __builtin_clz(L);
        int c1 = tbl[k * NB + lo];
        int c2 = tbl[k * NB + hi - (1 << k) + 1];
        if (c1 < m) m = c1;
        if (c2 < m) m = c2;
      }
    }
    if (l < 0 && 0 < m) m = 0;
    int h1 = (K1 == 0) ? 0 : (int)H[K1 - 1];
    int h2 = (K2 == 0) ? 0 : (int)H[K2 - 1];
    return h1 + h2 - 2 * m;
  };
  int u = spackU & 0x1FFF;
  int Ku = firstK[u];
  if (tid == 0) spackW = 0;
  __syncthreads();
  // distU pass (overwrites depthR region — depthR consumed)
  for (int v = tid; v < VV; v += nt) {
    int d = distq(Ku, firstK[v]);
    distU[v] = (unsigned short)d;
    atomicMax(&spackW, (d << 13) | v);
  }
  __syncthreads();
  int D = spackW >> 13;
  int w = spackW & 0x1FFF;
  int Kw = firstK[w];
  // distW pass into DEDICATED buffer (no prefmin aliasing)
  for (int v = tid; v < VV; v += nt) dbuf2[v] = (unsigned short)distq(Kw, firstK[v]);
  __syncthreads();
  {
    int half = D >> 1;
    for (int v = tid; v < VV; v += nt) {
      if ((int)distU[v] == half && (int)distU[v] + (int)dbuf2[v] == D) atomicMin(&scenter, v);
    }
  }
  __syncthreads();
  int cvert = (scenter == 0x7FFFFFFF) ? ROOT : scenter;
  int Kc = firstK[cvert];
  __syncthreads();
  // distC pass into dbuf2 (overwrites distW) + max depth
  for (int v = tid; v < VV; v += nt) {
    int d = distq(Kc, firstK[v]);
    dbuf2[v] = (unsigned short)d;
    atomicMax(&smaxd, d);
  }
  __syncthreads();
  int maxd = smaxd;
  int sTil = Kc;   // rotated tour rooted at c starts at orig position Kc
  // ---- parents under c: one rotated arc-pass (overwrites distU region) ----
  for (int a = tid; a < NA; a += nt) {
    int pa = NA - 1 - (int)r_a[a];
    int pb = NA - 1 - (int)r_a[a ^ 1];
    int pa2 = pa - sTil; if (pa2 < 0) pa2 += NA;
    int pb2 = pb - sTil; if (pb2 < 0) pb2 += NA;
    if (pa2 < pb2) {                     // down arc under c rooting: head's parent = tail
      int e = a >> 1;
      int head = (a & 1) ? mu[e] : mv[e];
      int tail = (a & 1) ? mv[e] : mu[e];
      parentS[head] = (unsigned short)tail;
    }
  }
  if (tid == 0) parentS[cvert] = (unsigned short)cvert;
  __syncthreads();
  // ---- Phase D: counting sort by dist-from-center ----
  for (int d = tid; d <= VV; d += nt) lev[d] = 0;
  __syncthreads();
  for (int v = tid; v < VV; v += nt) atomicAdd(&lev[dbuf2[v]], 1);
  __syncthreads();
  {
    const int SCH = 7;
    int base = tid * SCH;
    int s = 0;
    #pragma unroll
    for (int k = 0; k < SCH; k++) { int d = base + k; if (d <= VV) s += lev[d]; }
    part[tid] = s;
    __syncthreads();
    for (int d = 1; d < 1024; d <<= 1) {
      int add = (tid >= d) ? part[tid - d] : 0;
      __syncthreads();
      part[tid] += add;
      __syncthreads();
    }
    int ex = part[tid] - s;
    #pragma unroll
    for (int k = 0; k < SCH; k++) {
      int d = base + k;
      if (d <= VV) {
        int st = ex;
        ex += lev[d];
        if (d < VV) cur[d] = st;
        lpG[t * (VV + 1) + d] = st;
      }
    }
  }
  __syncthreads();
  for (int v = tid; v < VV; v += nt) {
    int d = dbuf2[v];
    int slot = atomicAdd(&cur[d], 1);
    ordS[slot] = (unsigned short)v;
    posS[v] = (unsigned short)slot;
  }
  __syncthreads();
  for (int j = tid; j < VV; j += nt) {
    int v = ordS[j];
    int pv = parentS[v];
    ordG[t * VV + j] = v;
    pvG[t * VV + j] = pv;
    spG[t * VV + j] = posS[pv];
  }
  if (tid == 0) nlevG[t] = maxd + 1;
}

// ---------------- K5: per-position weight to parent (edge-key reuse; root -> 1, unused) ----------------
__global__ void k_weights(const unsigned long long* __restrict__ ekey,
                          const int* __restrict__ ordG, const int* __restrict__ pvG,
                          float* __restrict__ wvp) {
  int i = blockIdx.x * blockDim.x + threadIdx.x;
  if (i >= TT * VV) return;
  int t = i / VV;
  int v = ordG[i], p = pvG[i];
  float wout;
  if (v == p) {
    wout = 1.0f;  // root (overridden in filter transform)
  } else {
    int a = v < p ? v : p;
    int diff = v < p ? p - v : v - p;
    int e;
    if (diff == WW) e = a;
    else { int r = a / WW, c = a - r * WW; e = EVERT + r * (WW - 1) + c; }
    unsigned long long k = ekey[(size_t)t * EE + e];
    double cost = __longlong_as_double((long long)(k & ~0x3FFFULL));
    wout = expf(-(float)cost / SIGMA_F);
  }
  wvp[i] = wout;
}

// ---------------- K6: tree filter — level-sweep up (wave 0), packed-float2 doubling down ----------------
// 512 threads (round-12 verbatim).
__global__ __launch_bounds__(512) void k_filter_pc(const float* __restrict__ Fsrc, float* __restrict__ Araw,
    const float* __restrict__ wvp, const int* __restrict__ ordG, const int* __restrict__ spG,
    const int* __restrict__ lpG, const int* __restrict__ nlevG, int treeBase) {
  int blk = blockIdx.x;
  int b = blk / CF, ch = blk - b * CF;
  int t = treeBase + b;
  __shared__ alignas(16) char arena[140816];
  float2* ab0 = (float2*)(arena);
  float2* ab1 = (float2*)(arena + 51200);
  float*  S   = (float*)(arena + 51200);     // dead after affine transform
  float*  w   = (float*)(arena + 76800);     // dead after affine transform
  unsigned short* sp0 = (unsigned short*)(arena + 102400);
  unsigned short* sp1 = (unsigned short*)(arena + 115200);
  unsigned short* lpS = (unsigned short*)(arena + 128000);  // u16[VV+1]
  const int* ord = ordG + t * VV;
  const int* spt = spG + t * VV;
  const float* wsrc = wvp + t * VV;
  const int* lp = lpG + t * (VV + 1);
  int tid = threadIdx.x;
  const int nt = 512;
  int NL = nlevG[t];
  for (int j = tid; j <= NL; j += nt) lpS[j] = (unsigned short)lp[j];
  const bool norm_in = (treeBase != 0);
  for (int j = tid; j < VV; j += nt) {
    sp0[j] = (unsigned short)spt[j];
    w[j] = wsrc[j];
    float val;
    if (ch < CP) {
      int v = ord[j];
      if (!norm_in) val = Fsrc[((size_t)b * CP + ch) * VV + v];
      else          val = Fsrc[((size_t)b * CF + ch) * VV + v] / Fsrc[((size_t)b * CF + CP) * VV + v];
    } else val = 1.0f;
    S[j] = val;
  }
  __syncthreads();
  // ---- up-sweep: wave 0 only, barrier-free, level bounds carried/prefetched ----
  if (tid < 64) {
    int s1 = lpS[NL];
    int s0 = lpS[NL - 1];
    for (int l = NL - 1; l >= 1; l--) {
      int s0n = (l > 1) ? (int)lpS[l - 1] : 0;
      for (int j = s0 + tid; j < s1; j += 64) {
        atomicAdd(&S[sp0[j]], w[j] * S[j]);
      }
      asm volatile("s_waitcnt lgkmcnt(0)" ::: "memory");
      __builtin_amdgcn_sched_barrier(0);
      s1 = s0; s0 = s0n;
    }
  }
  __syncthreads();
  // ---- transform to packed affine: ab0[j] = (a,b); root (pos 0) = (0, S[0]) ----
  for (int j = tid; j < VV; j += nt) {
    float wv = w[j];
    float a = (j == 0) ? 0.f : wv;
    float bv = (j == 0) ? S[0] : S[j] * (1.f - wv * wv);
    ab0[j] = make_float2(a, bv);
  }
  __syncthreads();
  // ---- down-sweep: packed affine pointer doubling with converged-lane skip ----
  int rounds = 0;
  { int d = 1; while (d < NL) { d <<= 1; rounds++; } }
  float2 *abs_ = ab0, *abd_ = ab1;
  unsigned short *ps_ = sp0, *pd_ = sp1;
  for (int r = 0; r < rounds; r++) {
    for (int j = tid; j < VV; j += nt) {
      float2 m = abs_[j];
      int p = ps_[j];
      float2 o = m;
      int pn = p;
      if (m.x != 0.f) {
        float2 mp = abs_[p];
        pn = ps_[p];
        o.x = m.x * mp.x;
        o.y = fmaf(m.x, mp.y, m.y);
      }
      abd_[j] = o;
      pd_[j] = (unsigned short)pn;
    }
    __syncthreads();
    float2* tf = abs_; abs_ = abd_; abd_ = tf;
    unsigned short* tu = ps_; ps_ = pd_; pd_ = tu;
  }
  // ---- scatter to vertex space ----
  float* Ob = Araw + ((size_t)b * CF + ch) * VV;
  for (int j = tid; j < VV; j += nt) Ob[ord[j]] = abs_[j].y;
}

// ---------------- K7: ROI-masked L1 loss (fused normalize of stage 2) ----------------
__global__ void k_loss(const float* __restrict__ prob, const float* __restrict__ Araw2,
                       const int* __restrict__ roi, double* __restrict__ acc) {
  int i = blockIdx.x * blockDim.x + threadIdx.x;
  int tid = threadIdx.x;
  double s = 0.0, n = 0.0;
  if (i < BB * VV) {
    int b = i / VV, v = i - b * VV;
    if (roi[i] != 0) {
      n = 1.0;
      const float* pb = prob + (size_t)b * CP * VV + v;
      const float* ab = Araw2 + (size_t)b * CF * VV + v;
      float inv = 1.0f / ab[CP * VV];
      float ls = 0.f;
      #pragma unroll
      for (int c = 0; c < CP; c++) ls += fabsf(pb[c * VV] - ab[c * VV] * inv);
      s = (double)ls;
    }
  }
  __shared__ double rs[256], rn[256];
  rs[tid] = s; rn[tid] = n;
  __syncthreads();
  for (int d = 128; d > 0; d >>= 1) {
    if (tid < d) { rs[tid] += rs[tid + d]; rn[tid] += rn[tid + d]; }
    __syncthreads();
  }
  if (tid == 0) { atomicAdd(&acc[0], rs[0]); atomicAdd(&acc[1], rn[0]); }
}

__global__ void k_finalize(const double* __restrict__ acc, float* __restrict__ out) {
  out[0] = (acc[1] > 0.0) ? (float)(acc[0] / acc[1]) : 0.0f;
}

extern "C" void kernel_launch(void* const* d_in, const int* in_sizes, int n_in,
                              void* d_out, int out_size, void* d_ws, size_t ws_size,
                              hipStream_t stream) {
  const float* preds = (const float*)d_in[0];
  const float* low   = (const float*)d_in[1];
  const float* high  = (const float*)d_in[2];
  const int*   roi   = (const int*)d_in[3];
  float* out = (float*)d_out;

  char* w = (char*)d_ws;
  size_t off = 0;
  auto alloc = [&](size_t bytes) -> void* {
    void* p = w + off;
    off += (bytes + 255) & ~(size_t)255;
    return p;
  };
  float* prob  = (float*)alloc((size_t)BB * CP * VV * 4);
  float* Araw1 = (float*)alloc((size_t)BB * CF * VV * 4);
  float* Araw2 = (float*)alloc((size_t)BB * CF * VV * 4);
  unsigned long long* ekey = (unsigned long long*)alloc((size_t)TT * EE * 8);
  int* mstU = (int*)alloc((size_t)TT * VV * 4);
  int* mstV = (int*)alloc((size_t)TT * VV * 4);
  int* ordG = (int*)alloc((size_t)TT * VV * 4);
  int* spG  = (int*)alloc((size_t)TT * VV * 4);
  int* pvG  = (int*)alloc((size_t)TT * VV * 4);
  int* lpG  = (int*)alloc((size_t)TT * (VV + 1) * 4);
  int* nlev = (int*)alloc((size_t)TT * 4);
  float* wvp = (float*)alloc((size_t)TT * VV * 4);
  double* acc = (double*)alloc(16);

  hipMemsetAsync(acc, 0, 16, stream);

  k_softmax<<<(BB * VV + 255) / 256, 256, 0, stream>>>(preds, prob);
  k_edgekey<<<(TT * EE + 255) / 256, 256, 0, stream>>>(low, high, ekey);
  k_boruvka<<<TT, 1024, 0, stream>>>(ekey, mstU, mstV);
  k_buildtree<<<TT, 1024, 0, stream>>>(mstU, mstV, ordG, spG, pvG, lpG, nlev);
  k_weights<<<(TT * VV + 255) / 256, 256, 0, stream>>>(ekey, ordG, pvG, wvp);
  k_filter_pc<<<BB * CF, 512, 0, stream>>>(prob,  Araw1, wvp, ordG, spG, lpG, nlev, 0);
  k_filter_pc<<<BB * CF, 512, 0, stream>>>(Araw1, Araw2, wvp, ordG, spG, lpG, nlev, BB);
  k_loss<<<(BB * VV + 255) / 256, 256, 0, stream>>>(prob, Araw2, roi, acc);
  k_finalize<<<1, 1, 0, stream>>>(acc, out);
}

// Round 17
// 366.150 us; speedup vs baseline: 1.1971x; 1.0316x over previous
//
#include <hip/hip_runtime.h>

#define BB 8
#define CP 21
#define CF 22
#define CLOW 3
#define CHIGH 256
#define WW 80
#define VV 6400
#define EVERT 6320
#define EE 12640
#define TT 16
#define SIGMA_F 0.002f
#define ROOT 3240          // seed vertex for tour break / diameter search

#define NE (VV - 1)        // tree edges
#define NA (2 * NE)        // Euler arcs = 12798
#define NILA 0xFFFFu
#define NB 200             // ceil(NA/64) RMQ blocks

__device__ __forceinline__ void edge_uv(int e, int& u, int& v) {
  if (e < EVERT) { u = e; v = e + WW; }
  else { int e2 = e - EVERT; int r = e2 / (WW - 1); int c = e2 - r * (WW - 1); u = r * WW + c; v = u + 1; }
}

// ---------------- K1: softmax over 21 channels, per pixel ----------------
__global__ void k_softmax(const float* __restrict__ preds, float* __restrict__ prob) {
  int i = blockIdx.x * blockDim.x + threadIdx.x;
  if (i >= BB * VV) return;
  int b = i / VV, v = i - b * VV;
  const float* p = preds + (size_t)b * CP * VV + v;
  float m = -1e30f;
  #pragma unroll
  for (int c = 0; c < CP; c++) m = fmaxf(m, p[c * VV]);
  float e[CP], s = 0.f;
  #pragma unroll
  for (int c = 0; c < CP; c++) { float x = expf(p[c * VV] - m); e[c] = x; s += x; }
  float inv = 1.f / s;
  float* o = prob + (size_t)b * CP * VV + v;
  #pragma unroll
  for (int c = 0; c < CP; c++) o[c * VV] = e[c] * inv;
}

// ---------------- K2: edge keys (float64 cost, top-50-bits | edge idx) ----------------
__global__ void k_edgekey(const float* __restrict__ low, const float* __restrict__ high,
                          unsigned long long* __restrict__ ekey) {
  int i = blockIdx.x * blockDim.x + threadIdx.x;
  if (i >= TT * EE) return;
  int t = i / EE, e = i - t * EE;
  int u, v; edge_uv(e, u, v);
  double acc = 0.0;
  if (t < BB) {
    const float* emb = low + (size_t)t * CLOW * VV;
    for (int c = 0; c < CLOW; c++) { double d = (double)emb[c * VV + u] - (double)emb[c * VV + v]; acc += d * d; }
  } else {
    const float* emb = high + (size_t)(t - BB) * CHIGH * VV;
    for (int c = 0; c < CHIGH; c++) { double d = (double)emb[c * VV + u] - (double)emb[c * VV + v]; acc += d * d; }
  }
  unsigned long long bits = (unsigned long long)__double_as_longlong(acc);
  ekey[i] = (bits & ~0x3FFFULL) | (unsigned long long)e;
}

// ---------------- K3: parallel Boruvka MST, edge compaction + barrier-free compression ----------------
__global__ __launch_bounds__(1024) void k_boruvka(const unsigned long long* __restrict__ ekey,
    int* __restrict__ mstU, int* __restrict__ mstV) {
  int t = blockIdx.x;
  const unsigned long long* key = ekey + (size_t)t * EE;
  int* mu = mstU + t * VV;
  int* mv = mstV + t * VV;
  __shared__ int comp[VV];
  __shared__ unsigned long long bst[VV];
  __shared__ unsigned short tgtS[VV];
  __shared__ unsigned short el0[EE];
  __shared__ unsigned short el1[EE];
  __shared__ int changed, cnt, necnt;
  int tid = threadIdx.x;
  const int nt = 1024;
  for (int v = tid; v < VV; v += nt) comp[v] = v;
  for (int e = tid; e < EE; e += nt) el0[e] = (unsigned short)e;
  if (tid == 0) cnt = 0;
  __syncthreads();
  unsigned short* els = el0;
  unsigned short* eld = el1;
  int ecnt = EE;
  for (int round = 0; round < 48 && ecnt > 0; round++) {
    for (int v = tid; v < VV; v += nt) bst[v] = ~0ULL;
    if (tid == 0) { changed = 0; necnt = 0; }
    __syncthreads();
    for (int j = tid; j < ecnt; j += nt) {
      int e = els[j];
      int u, v; edge_uv(e, u, v);
      int cu = comp[u], cv = comp[v];
      if (cu != cv) { unsigned long long k = key[e]; atomicMin(&bst[cu], k); atomicMin(&bst[cv], k); }
    }
    __syncthreads();
    for (int c = tid; c < VV; c += nt) {
      unsigned short tg = (unsigned short)NILA;
      if (comp[c] == c) {
        unsigned long long k = bst[c];
        if (k != ~0ULL) {
          int e = (int)(k & 0x3FFFULL);
          int u, v; edge_uv(e, u, v);
          int cu = comp[u], cv = comp[v];
          tg = (unsigned short)((cu == c) ? cv : cu);
        }
      }
      tgtS[c] = tg;
    }
    __syncthreads();
    for (int c = tid; c < VV; c += nt) {
      int o = tgtS[c];
      if (o == (int)NILA) continue;
      unsigned long long k = bst[c];
      if (bst[o] == k && c < o) continue;  // mutual minimum edge: smaller id stays root
      comp[c] = o;
      int slot = atomicAdd(&cnt, 1);
      int e = (int)(k & 0x3FFFULL);
      int u, v; edge_uv(e, u, v);
      mu[slot] = u; mv[slot] = v;
      changed = 1;
    }
    __syncthreads();
    if (!changed) break;
    // barrier-free full path compression
    for (int v = tid; v < VV; v += nt) {
      int c = comp[v];
      int c2 = comp[c];
      if (c2 != c) {
        int r0 = c2;
        while (true) { int n = comp[r0]; if (n == r0) break; r0 = n; }
        comp[v] = r0;
      }
    }
    __syncthreads();
    for (int j = tid; j < ecnt; j += nt) {
      int e = els[j];
      int u, v; edge_uv(e, u, v);
      if (comp[u] != comp[v]) { int s = atomicAdd(&necnt, 1); eld[s] = (unsigned short)e; }
    }
    __syncthreads();
    ecnt = necnt;
    __syncthreads();
    unsigned short* tp = els; els = eld; eld = tp;
  }
}

// ---------------- K4: Euler-tour rooting at the TRUE TREE CENTER ----------------
// Single ranking + single scan -> H; O(1) RMQ distances; wave-parallel RMQ build.
__global__ __launch_bounds__(1024) void k_buildtree(const int* __restrict__ mstU, const int* __restrict__ mstV,
    int* __restrict__ ordG, int* __restrict__ spG, int* __restrict__ pvG,
    int* __restrict__ lpG, int* __restrict__ nlevG) {
  int t = blockIdx.x;
  const int* mu = mstU + t * VV;
  const int* mv = mstV + t * VV;
  int tid = threadIdx.x;
  const int nt = 1024;

  __shared__ int buf4[32004];            // 128016-byte phase-overlapped arena
  char* buf = (char*)buf4;
  __shared__ int part[1024];
  __shared__ short tbl[8 * NB];
  __shared__ unsigned short dbuf2[VV];   // dedicated distW/distC (no aliasing)
  __shared__ int lasts, spackU, spackW, scenter, smaxd;

  // Phase A regions
  int* deg = (int*)(buf + 0);
  int* off = (int*)(buf + 25600);
  unsigned short* adjA = (unsigned short*)(buf + 51208);
  unsigned short* succ = (unsigned short*)(buf + 76808);
  // Ranking scratch
  unsigned short* r_a = (unsigned short*)(buf + 0);
  unsigned short* r_y = (unsigned short*)(buf + 102408);
  unsigned short* nx_y = (unsigned short*)(buf + 25600);
  // Tour profile + RMQ
  short* H = (short*)(buf + 51208);                        // adjA dead
  unsigned short* depthR = (unsigned short*)(buf + 76808); // succ dead
  unsigned short* firstK = (unsigned short*)(buf + 89608);
  short* prefmin = (short*)(buf + 102408);                 // r_y dead
  short* sufmin  = (short*)(buf + 25600);                  // nx_y dead
  unsigned short* distU = (unsigned short*)(buf + 76808);  // overwrites depthR (after u-select)
  unsigned short* parentS = (unsigned short*)(buf + 76808);// overwrites distU (after c-select)
  // Phase D
  int* lev = (int*)(buf + 25600);                          // sufmin dead
  int* cur = (int*)(buf + 51208);                          // H dead
  unsigned short* ordS = (unsigned short*)(buf + 89608);   // firstK dead
  unsigned short* posS = (unsigned short*)(buf + 102408);  // prefmin dead

  // ---- Phase A: CSR + Euler successors ----
  for (int v = tid; v < VV; v += nt) deg[v] = 0;
  __syncthreads();
  for (int e = tid; e < NE; e += nt) { atomicAdd(&deg[mu[e]], 1); atomicAdd(&deg[mv[e]], 1); }
  __syncthreads();
  {
    const int SCH = 7;
    int base = tid * SCH;
    int s = 0;
    #pragma unroll
    for (int k = 0; k < SCH; k++) { int v = base + k; if (v < VV) s += deg[v]; }
    part[tid] = s;
    __syncthreads();
    for (int d = 1; d < 1024; d <<= 1) {
      int add = (tid >= d) ? part[tid - d] : 0;
      __syncthreads();
      part[tid] += add;
      __syncthreads();
    }
    int ex = part[tid] - s;
    #pragma unroll
    for (int k = 0; k < SCH; k++) { int v = base + k; if (v < VV) { off[v] = ex; ex += deg[v]; } }
    if (tid == 1023) off[VV] = ex;
  }
  __syncthreads();
  for (int v = tid; v < VV; v += nt) deg[v] = off[v];   // cursors
  __syncthreads();
  for (int e = tid; e < NE; e += nt) {
    int u = mu[e], v = mv[e];
    adjA[atomicAdd(&deg[u], 1)] = (unsigned short)(2 * e);       // arc u->v (head = v)
    adjA[atomicAdd(&deg[v], 1)] = (unsigned short)(2 * e + 1);   // arc v->u (head = u)
  }
  __syncthreads();
  for (int v = tid; v < VV; v += nt) {
    int b0 = off[v], dv = off[v + 1] - b0;
    for (int k = 0; k < dv; k++) {
      unsigned short a = adjA[b0 + k];
      unsigned short b = adjA[b0 + ((k + 1 == dv) ? 0 : k + 1)];
      succ[a ^ 1] = b;
    }
  }
  if (tid == 0) lasts = adjA[off[ROOT] + (off[ROOT + 1] - off[ROOT]) - 1] ^ 1;
  __syncthreads();
  if (tid == 0) succ[lasts] = (unsigned short)NILA;
  __syncthreads();
  // ---- Phase B: list ranking ----
  for (int a = tid; a < NA; a += nt) r_a[a] = (succ[a] == (unsigned short)NILA) ? 0 : 1;
  __syncthreads();
  {
    unsigned short *rx = r_a, *ry = r_y, *nxp = succ, *nyp = nx_y;
    for (int rd = 0; rd < 14; rd++) {
      for (int a = tid; a < NA; a += nt) {
        unsigned short n = nxp[a];
        if (n == (unsigned short)NILA) { ry[a] = rx[a]; nyp[a] = (unsigned short)NILA; }
        else { ry[a] = rx[a] + rx[n]; nyp[a] = nxp[n]; }
      }
      __syncthreads();
      unsigned short* tp;
      tp = rx; rx = ry; ry = tp;
      tp = nxp; nxp = nyp; nyp = tp;
    }
  }
  // ---- tour values + single inclusive scan -> H ----
  for (int a = tid; a < NA; a += nt) {
    int pa = NA - 1 - (int)r_a[a];
    int pb = NA - 1 - (int)r_a[a ^ 1];
    H[pa] = (pa < pb) ? (short)1 : (short)-1;
  }
  __syncthreads();
  {
    const int SCH = 13;
    int base = tid * SCH;
    int lim = base + SCH; if (lim > NA) lim = NA;
    int s = 0;
    for (int j = base; j < lim; j++) s += H[j];
    part[tid] = s;
    __syncthreads();
    for (int d = 1; d < 1024; d <<= 1) {
      int add = (tid >= d) ? part[tid - d] : 0;
      __syncthreads();
      part[tid] += add;
      __syncthreads();
    }
    int run = part[tid] - s;
    for (int j = base; j < lim; j++) { run += H[j]; H[j] = (short)run; }
  }
  __syncthreads();
  // ---- extract original-root depths + entry steps K ----
  if (tid == 0) { spackU = 0; smaxd = 0; scenter = 0x7FFFFFFF; }
  __syncthreads();
  for (int a = tid; a < NA; a += nt) {
    int pa = NA - 1 - (int)r_a[a];
    int pb = NA - 1 - (int)r_a[a ^ 1];
    if (pa < pb) {                       // down arc under ROOT rooting
      int e = a >> 1;
      int head = (a & 1) ? mu[e] : mv[e];
      depthR[head] = (unsigned short)H[pa];
      firstK[head] = (unsigned short)(pa + 1);
    }
  }
  if (tid == 0) { depthR[ROOT] = 0; firstK[ROOT] = 0; }
  __syncthreads();
  for (int v = tid; v < VV; v += nt) atomicMax(&spackU, ((int)depthR[v] << 13) | v);
  __syncthreads();
  // ---- RMQ build: WAVE-PARALLEL segmented min-scan (64-elem segment == wave64) ----
  {
    int lane = tid & 63;
    int wid = tid >> 6;                    // 16 waves
    for (int seg = wid; seg < NB; seg += 16) {
      int p = seg * 64 + lane;
      int h = (p < NA) ? (int)H[p] : 32767;
      int hp = h;
      #pragma unroll
      for (int d = 1; d < 64; d <<= 1) {   // inclusive prefix-min
        int o = __shfl_up(hp, d);
        if (lane >= d && o < hp) hp = o;
      }
      prefmin[p] = (short)hp;
      int hs = h;
      #pragma unroll
      for (int d = 1; d < 64; d <<= 1) {   // inclusive suffix-min
        int o = __shfl_down(hs, d);
        if (lane + d < 64 && o < hs) hs = o;
      }
      sufmin[p] = (short)hs;
      if (lane == 0) tbl[seg] = (short)hs;
    }
  }
  __syncthreads();
  for (int k = 1; k < 8; k++) {
    short vv_ = 0;
    if (tid < NB) {
      int o = tid + (1 << (k - 1));
      short a = tbl[(k - 1) * NB + tid];
      short b2 = (o < NB) ? tbl[(k - 1) * NB + o] : (short)32767;
      vv_ = (a < b2) ? a : b2;
    }
    __syncthreads();
    if (tid < NB) tbl[k * NB + tid] = vv_;
    __syncthreads();
  }
  // O(1)-ish tree distance between entry-steps K1, K2
  auto distq = [&](int K1, int K2) -> int {
    if (K1 == K2) return 0;
    int l = (K1 < K2 ? K1 : K2) - 1;
    int r = (K1 > K2 ? K1 : K2) - 1;
    int m = 32767;
    int l0 = l < 0 ? 0 : l;
    int bl = l0 >> 6, br = r >> 6;
    if (bl == br) {
      for (int p = l0; p <= r; p++) { int h = H[p]; if (h < m) m = h; }
    } else {
      int a = sufmin[l0], b2 = prefmin[r];
      m = a < b2 ? a : b2;
      int lo = bl + 1, hi = br - 1;
      if (lo <= hi) {
        int L = hi - lo + 1;
        int k = 31 - __builtin_clz(L);
        int c1 = tbl[k * NB + lo];
        int c2 = tbl[k * NB + hi - (1 << k) + 1];
        if (c1 < m) m = c1;
        if (c2 < m) m = c2;
      }
    }
    if (l < 0 && 0 < m) m = 0;
    int h1 = (K1 == 0) ? 0 : (int)H[K1 - 1];
    int h2 = (K2 == 0) ? 0 : (int)H[K2 - 1];
    return h1 + h2 - 2 * m;
  };
  int u = spackU & 0x1FFF;
  int Ku = firstK[u];
  if (tid == 0) spackW = 0;
  __syncthreads();
  // distU pass (overwrites depthR region — depthR consumed)
  for (int v = tid; v < VV; v += nt) {
    int d = distq(Ku, firstK[v]);
    distU[v] = (unsigned short)d;
    atomicMax(&spackW, (d << 13) | v);
  }
  __syncthreads();
  int D = spackW >> 13;
  int w = spackW & 0x1FFF;
  int Kw = firstK[w];
  for (int v = tid; v < VV; v += nt) dbuf2[v] = (unsigned short)distq(Kw, firstK[v]);
  __syncthreads();
  {
    int half = D >> 1;
    for (int v = tid; v < VV; v += nt) {
      if ((int)distU[v] == half && (int)distU[v] + (int)dbuf2[v] == D) atomicMin(&scenter, v);
    }
  }
  __syncthreads();
  int cvert = (scenter == 0x7FFFFFFF) ? ROOT : scenter;
  int Kc = firstK[cvert];
  __syncthreads();
  // distC pass into dbuf2 (overwrites distW) + max depth
  for (int v = tid; v < VV; v += nt) {
    int d = distq(Kc, firstK[v]);
    dbuf2[v] = (unsigned short)d;
    atomicMax(&smaxd, d);
  }
  __syncthreads();
  int maxd = smaxd;
  int sTil = Kc;   // rotated tour rooted at c starts at orig position Kc
  // ---- parents under c: one rotated arc-pass (overwrites distU region) ----
  for (int a = tid; a < NA; a += nt) {
    int pa = NA - 1 - (int)r_a[a];
    int pb = NA - 1 - (int)r_a[a ^ 1];
    int pa2 = pa - sTil; if (pa2 < 0) pa2 += NA;
    int pb2 = pb - sTil; if (pb2 < 0) pb2 += NA;
    if (pa2 < pb2) {                     // down arc under c rooting: head's parent = tail
      int e = a >> 1;
      int head = (a & 1) ? mu[e] : mv[e];
      int tail = (a & 1) ? mv[e] : mu[e];
      parentS[head] = (unsigned short)tail;
    }
  }
  if (tid == 0) parentS[cvert] = (unsigned short)cvert;
  __syncthreads();
  // ---- Phase D: counting sort by dist-from-center ----
  for (int d = tid; d <= VV; d += nt) lev[d] = 0;
  __syncthreads();
  for (int v = tid; v < VV; v += nt) atomicAdd(&lev[dbuf2[v]], 1);
  __syncthreads();
  {
    const int SCH = 7;
    int base = tid * SCH;
    int s = 0;
    #pragma unroll
    for (int k = 0; k < SCH; k++) { int d = base + k; if (d <= VV) s += lev[d]; }
    part[tid] = s;
    __syncthreads();
    for (int d = 1; d < 1024; d <<= 1) {
      int add = (tid >= d) ? part[tid - d] : 0;
      __syncthreads();
      part[tid] += add;
      __syncthreads();
    }
    int ex = part[tid] - s;
    #pragma unroll
    for (int k = 0; k < SCH; k++) {
      int d = base + k;
      if (d <= VV) {
        int st = ex;
        ex += lev[d];
        if (d < VV) cur[d] = st;
        lpG[t * (VV + 1) + d] = st;
      }
    }
  }
  __syncthreads();
  for (int v = tid; v < VV; v += nt) {
    int d = dbuf2[v];
    int slot = atomicAdd(&cur[d], 1);
    ordS[slot] = (unsigned short)v;
    posS[v] = (unsigned short)slot;
  }
  __syncthreads();
  for (int j = tid; j < VV; j += nt) {
    int v = ordS[j];
    int pv = parentS[v];
    ordG[t * VV + j] = v;
    pvG[t * VV + j] = pv;
    spG[t * VV + j] = posS[pv];
  }
  if (tid == 0) nlevG[t] = maxd + 1;
}

// ---------------- K5: per-position weight to parent (edge-key reuse; root -> 1, unused) ----------------
__global__ void k_weights(const unsigned long long* __restrict__ ekey,
                          const int* __restrict__ ordG, const int* __restrict__ pvG,
                          float* __restrict__ wvp) {
  int i = blockIdx.x * blockDim.x + threadIdx.x;
  if (i >= TT * VV) return;
  int t = i / VV;
  int v = ordG[i], p = pvG[i];
  float wout;
  if (v == p) {
    wout = 1.0f;  // root (overridden in filter transform)
  } else {
    int a = v < p ? v : p;
    int diff = v < p ? p - v : v - p;
    int e;
    if (diff == WW) e = a;
    else { int r = a / WW, c = a - r * WW; e = EVERT + r * (WW - 1) + c; }
    unsigned long long k = ekey[(size_t)t * EE + e];
    double cost = __longlong_as_double((long long)(k & ~0x3FFFULL));
    wout = expf(-(float)cost / SIGMA_F);
  }
  wvp[i] = wout;
}

// ---------------- K6: tree filter — level-sweep up (wave 0), packed-float2 doubling down ----------------
// 512 threads (round-12 verbatim).
__global__ __launch_bounds__(512) void k_filter_pc(const float* __restrict__ Fsrc, float* __restrict__ Araw,
    const float* __restrict__ wvp, const int* __restrict__ ordG, const int* __restrict__ spG,
    const int* __restrict__ lpG, const int* __restrict__ nlevG, int treeBase) {
  int blk = blockIdx.x;
  int b = blk / CF, ch = blk - b * CF;
  int t = treeBase + b;
  __shared__ alignas(16) char arena[140816];
  float2* ab0 = (float2*)(arena);
  float2* ab1 = (float2*)(arena + 51200);
  float*  S   = (float*)(arena + 51200);     // dead after affine transform
  float*  w   = (float*)(arena + 76800);     // dead after affine transform
  unsigned short* sp0 = (unsigned short*)(arena + 102400);
  unsigned short* sp1 = (unsigned short*)(arena + 115200);
  unsigned short* lpS = (unsigned short*)(arena + 128000);  // u16[VV+1]
  const int* ord = ordG + t * VV;
  const int* spt = spG + t * VV;
  const float* wsrc = wvp + t * VV;
  const int* lp = lpG + t * (VV + 1);
  int tid = threadIdx.x;
  const int nt = 512;
  int NL = nlevG[t];
  for (int j = tid; j <= NL; j += nt) lpS[j] = (unsigned short)lp[j];
  const bool norm_in = (treeBase != 0);
  for (int j = tid; j < VV; j += nt) {
    sp0[j] = (unsigned short)spt[j];
    w[j] = wsrc[j];
    float val;
    if (ch < CP) {
      int v = ord[j];
      if (!norm_in) val = Fsrc[((size_t)b * CP + ch) * VV + v];
      else          val = Fsrc[((size_t)b * CF + ch) * VV + v] / Fsrc[((size_t)b * CF + CP) * VV + v];
    } else val = 1.0f;
    S[j] = val;
  }
  __syncthreads();
  // ---- up-sweep: wave 0 only, barrier-free, level bounds carried/prefetched ----
  if (tid < 64) {
    int s1 = lpS[NL];
    int s0 = lpS[NL - 1];
    for (int l = NL - 1; l >= 1; l--) {
      int s0n = (l > 1) ? (int)lpS[l - 1] : 0;
      for (int j = s0 + tid; j < s1; j += 64) {
        atomicAdd(&S[sp0[j]], w[j] * S[j]);
      }
      asm volatile("s_waitcnt lgkmcnt(0)" ::: "memory");
      __builtin_amdgcn_sched_barrier(0);
      s1 = s0; s0 = s0n;
    }
  }
  __syncthreads();
  // ---- transform to packed affine: ab0[j] = (a,b); root (pos 0) = (0, S[0]) ----
  for (int j = tid; j < VV; j += nt) {
    float wv = w[j];
    float a = (j == 0) ? 0.f : wv;
    float bv = (j == 0) ? S[0] : S[j] * (1.f - wv * wv);
    ab0[j] = make_float2(a, bv);
  }
  __syncthreads();
  // ---- down-sweep: packed affine pointer doubling with converged-lane skip ----
  int rounds = 0;
  { int d = 1; while (d < NL) { d <<= 1; rounds++; } }
  float2 *abs_ = ab0, *abd_ = ab1;
  unsigned short *ps_ = sp0, *pd_ = sp1;
  for (int r = 0; r < rounds; r++) {
    for (int j = tid; j < VV; j += nt) {
      float2 m = abs_[j];
      int p = ps_[j];
      float2 o = m;
      int pn = p;
      if (m.x != 0.f) {
        float2 mp = abs_[p];
        pn = ps_[p];
        o.x = m.x * mp.x;
        o.y = fmaf(m.x, mp.y, m.y);
      }
      abd_[j] = o;
      pd_[j] = (unsigned short)pn;
    }
    __syncthreads();
    float2* tf = abs_; abs_ = abd_; abd_ = tf;
    unsigned short* tu = ps_; ps_ = pd_; pd_ = tu;
  }
  // ---- scatter to vertex space ----
  float* Ob = Araw + ((size_t)b * CF + ch) * VV;
  for (int j = tid; j < VV; j += nt) Ob[ord[j]] = abs_[j].y;
}

// ---------------- K7: ROI-masked L1 loss (fused normalize of stage 2) ----------------
__global__ void k_loss(const float* __restrict__ prob, const float* __restrict__ Araw2,
                       const int* __restrict__ roi, double* __restrict__ acc) {
  int i = blockIdx.x * blockDim.x + threadIdx.x;
  int tid = threadIdx.x;
  double s = 0.0, n = 0.0;
  if (i < BB * VV) {
    int b = i / VV, v = i - b * VV;
    if (roi[i] != 0) {
      n = 1.0;
      const float* pb = prob + (size_t)b * CP * VV + v;
      const float* ab = Araw2 + (size_t)b * CF * VV + v;
      float inv = 1.0f / ab[CP * VV];
      float ls = 0.f;
      #pragma unroll
      for (int c = 0; c < CP; c++) ls += fabsf(pb[c * VV] - ab[c * VV] * inv);
      s = (double)ls;
    }
  }
  __shared__ double rs[256], rn[256];
  rs[tid] = s; rn[tid] = n;
  __syncthreads();
  for (int d = 128; d > 0; d >>= 1) {
    if (tid < d) { rs[tid] += rs[tid + d]; rn[tid] += rn[tid + d]; }
    __syncthreads();
  }
  if (tid == 0) { atomicAdd(&acc[0], rs[0]); atomicAdd(&acc[1], rn[0]); }
}

__global__ void k_finalize(const double* __restrict__ acc, float* __restrict__ out) {
  out[0] = (acc[1] > 0.0) ? (float)(acc[0] / acc[1]) : 0.0f;
}

extern "C" void kernel_launch(void* const* d_in, const int* in_sizes, int n_in,
                              void* d_out, int out_size, void* d_ws, size_t ws_size,
                              hipStream_t stream) {
  const float* preds = (const float*)d_in[0];
  const float* low   = (const float*)d_in[1];
  const float* high  = (const float*)d_in[2];
  const int*   roi   = (const int*)d_in[3];
  float* out = (float*)d_out;

  char* w = (char*)d_ws;
  size_t off = 0;
  auto alloc = [&](size_t bytes) -> void* {
    void* p = w + off;
    off += (bytes + 255) & ~(size_t)255;
    return p;
  };
  float* prob  = (float*)alloc((size_t)BB * CP * VV * 4);
  float* Araw1 = (float*)alloc((size_t)BB * CF * VV * 4);
  float* Araw2 = (float*)alloc((size_t)BB * CF * VV * 4);
  unsigned long long* ekey = (unsigned long long*)alloc((size_t)TT * EE * 8);
  int* mstU = (int*)alloc((size_t)TT * VV * 4);
  int* mstV = (int*)alloc((size_t)TT * VV * 4);
  int* ordG = (int*)alloc((size_t)TT * VV * 4);
  int* spG  = (int*)alloc((size_t)TT * VV * 4);
  int* pvG  = (int*)alloc((size_t)TT * VV * 4);
  int* lpG  = (int*)alloc((size_t)TT * (VV + 1) * 4);
  int* nlev = (int*)alloc((size_t)TT * 4);
  float* wvp = (float*)alloc((size_t)TT * VV * 4);
  double* acc = (double*)alloc(16);

  hipMemsetAsync(acc, 0, 16, stream);

  k_softmax<<<(BB * VV + 255) / 256, 256, 0, stream>>>(preds, prob);
  k_edgekey<<<(TT * EE + 255) / 256, 256, 0, stream>>>(low, high, ekey);
  k_boruvka<<<TT, 1024, 0, stream>>>(ekey, mstU, mstV);
  k_buildtree<<<TT, 1024, 0, stream>>>(mstU, mstV, ordG, spG, pvG, lpG, nlev);
  k_weights<<<(TT * VV + 255) / 256, 256, 0, stream>>>(ekey, ordG, pvG, wvp);
  k_filter_pc<<<BB * CF, 512, 0, stream>>>(prob,  Araw1, wvp, ordG, spG, lpG, nlev, 0);
  k_filter_pc<<<BB * CF, 512, 0, stream>>>(Araw1, Araw2, wvp, ordG, spG, lpG, nlev, BB);
  k_loss<<<(BB * VV + 255) / 256, 256, 0, stream>>>(prob, Araw2, roi, acc);
  k_finalize<<<1, 1, 0, stream>>>(acc, out);
}

// Round 18
// 300.121 us; speedup vs baseline: 1.4605x; 1.2200x over previous
//
#include <hip/hip_runtime.h>

#define BB 8
#define CP 21
#define CF 22
#define CLOW 3
#define CHIGH 256
#define WW 80
#define VV 6400
#define EVERT 6320
#define EE 12640
#define TT 16
#define SIGMA_F 0.002f
#define ROOT 3240          // seed vertex for tour break / diameter search

#define NE (VV - 1)        // tree edges
#define NA (2 * NE)        // Euler arcs = 12798
#define NILA 0xFFFFu
#define NB 200             // ceil(NA/64) RMQ blocks

__device__ __forceinline__ void edge_uv(int e, int& u, int& v) {
  if (e < EVERT) { u = e; v = e + WW; }
  else { int e2 = e - EVERT; int r = e2 / (WW - 1); int c = e2 - r * (WW - 1); u = r * WW + c; v = u + 1; }
}

// ---------------- K1: softmax over 21 channels, per pixel ----------------
__global__ void k_softmax(const float* __restrict__ preds, float* __restrict__ prob) {
  int i = blockIdx.x * blockDim.x + threadIdx.x;
  if (i >= BB * VV) return;
  int b = i / VV, v = i - b * VV;
  const float* p = preds + (size_t)b * CP * VV + v;
  float m = -1e30f;
  #pragma unroll
  for (int c = 0; c < CP; c++) m = fmaxf(m, p[c * VV]);
  float e[CP], s = 0.f;
  #pragma unroll
  for (int c = 0; c < CP; c++) { float x = expf(p[c * VV] - m); e[c] = x; s += x; }
  float inv = 1.f / s;
  float* o = prob + (size_t)b * CP * VV + v;
  #pragma unroll
  for (int c = 0; c < CP; c++) o[c * VV] = e[c] * inv;
}

// ---------------- K2: edge keys (float64 cost, top-50-bits | edge idx) ----------------
__global__ void k_edgekey(const float* __restrict__ low, const float* __restrict__ high,
                          unsigned long long* __restrict__ ekey) {
  int i = blockIdx.x * blockDim.x + threadIdx.x;
  if (i >= TT * EE) return;
  int t = i / EE, e = i - t * EE;
  int u, v; edge_uv(e, u, v);
  double acc = 0.0;
  if (t < BB) {
    const float* emb = low + (size_t)t * CLOW * VV;
    for (int c = 0; c < CLOW; c++) { double d = (double)emb[c * VV + u] - (double)emb[c * VV + v]; acc += d * d; }
  } else {
    const float* emb = high + (size_t)(t - BB) * CHIGH * VV;
    for (int c = 0; c < CHIGH; c++) { double d = (double)emb[c * VV + u] - (double)emb[c * VV + v]; acc += d * d; }
  }
  unsigned long long bits = (unsigned long long)__double_as_longlong(acc);
  ekey[i] = (bits & ~0x3FFFULL) | (unsigned long long)e;
}

// ---------------- K3: parallel Boruvka MST, edge compaction + barrier-free compression ----------------
__global__ __launch_bounds__(1024) void k_boruvka(const unsigned long long* __restrict__ ekey,
    int* __restrict__ mstU, int* __restrict__ mstV) {
  int t = blockIdx.x;
  const unsigned long long* key = ekey + (size_t)t * EE;
  int* mu = mstU + t * VV;
  int* mv = mstV + t * VV;
  __shared__ int comp[VV];
  __shared__ unsigned long long bst[VV];
  __shared__ unsigned short tgtS[VV];
  __shared__ unsigned short el0[EE];
  __shared__ unsigned short el1[EE];
  __shared__ int changed, cnt, necnt;
  int tid = threadIdx.x;
  const int nt = 1024;
  for (int v = tid; v < VV; v += nt) comp[v] = v;
  for (int e = tid; e < EE; e += nt) el0[e] = (unsigned short)e;
  if (tid == 0) cnt = 0;
  __syncthreads();
  unsigned short* els = el0;
  unsigned short* eld = el1;
  int ecnt = EE;
  for (int round = 0; round < 48 && ecnt > 0; round++) {
    for (int v = tid; v < VV; v += nt) bst[v] = ~0ULL;
    if (tid == 0) { changed = 0; necnt = 0; }
    __syncthreads();
    for (int j = tid; j < ecnt; j += nt) {
      int e = els[j];
      int u, v; edge_uv(e, u, v);
      int cu = comp[u], cv = comp[v];
      if (cu != cv) { unsigned long long k = key[e]; atomicMin(&bst[cu], k); atomicMin(&bst[cv], k); }
    }
    __syncthreads();
    for (int c = tid; c < VV; c += nt) {
      unsigned short tg = (unsigned short)NILA;
      if (comp[c] == c) {
        unsigned long long k = bst[c];
        if (k != ~0ULL) {
          int e = (int)(k & 0x3FFFULL);
          int u, v; edge_uv(e, u, v);
          int cu = comp[u], cv = comp[v];
          tg = (unsigned short)((cu == c) ? cv : cu);
        }
      }
      tgtS[c] = tg;
    }
    __syncthreads();
    for (int c = tid; c < VV; c += nt) {
      int o = tgtS[c];
      if (o == (int)NILA) continue;
      unsigned long long k = bst[c];
      if (bst[o] == k && c < o) continue;  // mutual minimum edge: smaller id stays root
      comp[c] = o;
      int slot = atomicAdd(&cnt, 1);
      int e = (int)(k & 0x3FFFULL);
      int u, v; edge_uv(e, u, v);
      mu[slot] = u; mv[slot] = v;
      changed = 1;
    }
    __syncthreads();
    if (!changed) break;
    // barrier-free full path compression
    for (int v = tid; v < VV; v += nt) {
      int c = comp[v];
      int c2 = comp[c];
      if (c2 != c) {
        int r0 = c2;
        while (true) { int n = comp[r0]; if (n == r0) break; r0 = n; }
        comp[v] = r0;
      }
    }
    __syncthreads();
    for (int j = tid; j < ecnt; j += nt) {
      int e = els[j];
      int u, v; edge_uv(e, u, v);
      if (comp[u] != comp[v]) { int s = atomicAdd(&necnt, 1); eld[s] = (unsigned short)e; }
    }
    __syncthreads();
    ecnt = necnt;
    __syncthreads();
    unsigned short* tp = els; els = eld; eld = tp;
  }
}

// ---------------- K4: Euler-tour rooting at the TRUE TREE CENTER ----------------
// Packed int ranking (rank<<16|next), shfl-based scans (2 barriers), wave-reduced argmax.
__global__ __launch_bounds__(1024) void k_buildtree(const int* __restrict__ mstU, const int* __restrict__ mstV,
    int* __restrict__ ordG, int* __restrict__ spG, int* __restrict__ pvG,
    int* __restrict__ lpG, int* __restrict__ nlevG) {
  int t = blockIdx.x;
  const int* mu = mstU + t * VV;
  const int* mv = mstV + t * VV;
  int tid = threadIdx.x;
  const int nt = 1024;
  int lane = tid & 63, wid = tid >> 6;

  __shared__ int buf4[32004];            // 128016-byte phase-overlapped arena
  char* buf = (char*)buf4;
  __shared__ int part[64];
  __shared__ short tbl[8 * NB];
  __shared__ unsigned short dbuf2[VV];   // dedicated distW/distC
  __shared__ int lasts, spackU, spackW, scenter, smaxd;

  // Phase A regions
  int* deg = (int*)(buf + 0);
  int* off = (int*)(buf + 25600);
  unsigned short* adjA = (unsigned short*)(buf + 51208);   // [51208,76804)
  unsigned short* succ = (unsigned short*)(buf + 102408);  // [102408,128004)
  // Packed ranking
  int* pk0 = (int*)(buf + 0);                              // [0,51192)   (deg/off dead)
  int* pk1 = (int*)(buf + 51208);                          // [51208,102400) (adjA dead)
  unsigned short* r_a = (unsigned short*)(buf + 102408);   // [102408,128004) (succ dead after pk init)
  // Tour profile + RMQ
  short* H = (short*)(buf + 51208);                        // [51208,76804)  (pk1 dead)
  unsigned short* depthR = (unsigned short*)(buf + 76808); // [76808,89608)
  unsigned short* firstK = (unsigned short*)(buf + 89608); // [89608,102408)
  short* prefmin = (short*)(buf + 0);                      // [0,25596)   (pk0 dead)
  short* sufmin  = (short*)(buf + 25600);                  // [25600,51196)
  unsigned short* distU = (unsigned short*)(buf + 76808);  // overwrites depthR
  unsigned short* parentS = (unsigned short*)(buf + 76808);// overwrites distU (after c-select)
  // Phase D
  int* lev = (int*)(buf + 0);                              // [0,25604)   (prefmin dead)
  int* cur = (int*)(buf + 25604);                          // [25604,51204) (sufmin dead)
  unsigned short* ordS = (unsigned short*)(buf + 51208);   // [51208,64008) (H dead)
  unsigned short* posS = (unsigned short*)(buf + 64008);   // [64008,76808)

  // shfl-based block exclusive-prefix helper (inclusive wave scan + wave offsets)
  auto blockScanEx = [&](int s) -> int {
    int x = s;
    #pragma unroll
    for (int d = 1; d < 64; d <<= 1) { int o = __shfl_up(x, d); if (lane >= d) x += o; }
    if (lane == 63) part[wid] = x;
    __syncthreads();
    if (wid == 0) {
      int y = (lane < 16) ? part[lane] : 0;
      #pragma unroll
      for (int d = 1; d < 16; d <<= 1) { int o = __shfl_up(y, d); if (lane >= d) y += o; }
      if (lane < 16) part[lane] = y;
    }
    __syncthreads();
    int base = (wid > 0) ? part[wid - 1] : 0;
    return base + (x - s);
  };

  // ---- Phase A: CSR + Euler successors ----
  for (int v = tid; v < VV; v += nt) deg[v] = 0;
  __syncthreads();
  for (int e = tid; e < NE; e += nt) { atomicAdd(&deg[mu[e]], 1); atomicAdd(&deg[mv[e]], 1); }
  __syncthreads();
  {
    const int SCH = 7;
    int base = tid * SCH;
    int s = 0;
    #pragma unroll
    for (int k = 0; k < SCH; k++) { int v = base + k; if (v < VV) s += deg[v]; }
    int ex = blockScanEx(s);
    #pragma unroll
    for (int k = 0; k < SCH; k++) { int v = base + k; if (v < VV) { off[v] = ex; ex += deg[v]; } }
    if (tid == 1023) off[VV] = ex;
  }
  __syncthreads();
  for (int v = tid; v < VV; v += nt) deg[v] = off[v];   // cursors
  __syncthreads();
  for (int e = tid; e < NE; e += nt) {
    int u = mu[e], v = mv[e];
    adjA[atomicAdd(&deg[u], 1)] = (unsigned short)(2 * e);       // arc u->v (head = v)
    adjA[atomicAdd(&deg[v], 1)] = (unsigned short)(2 * e + 1);   // arc v->u (head = u)
  }
  __syncthreads();
  for (int v = tid; v < VV; v += nt) {
    int b0 = off[v], dv = off[v + 1] - b0;
    for (int k = 0; k < dv; k++) {
      unsigned short a = adjA[b0 + k];
      unsigned short b = adjA[b0 + ((k + 1 == dv) ? 0 : k + 1)];
      succ[a ^ 1] = b;
    }
  }
  if (tid == 0) lasts = adjA[off[ROOT] + (off[ROOT + 1] - off[ROOT]) - 1] ^ 1;
  __syncthreads();
  if (tid == 0) succ[lasts] = (unsigned short)NILA;
  __syncthreads();
  // ---- Phase B: PACKED list ranking: pk = (rank<<16)|next ----
  // init pk0 from succ (deg/off dead; succ region becomes r_a afterwards)
  for (int a = tid; a < NA; a += nt) {
    unsigned int n = succ[a];
    pk0[a] = ((n == NILA ? 0 : 1) << 16) | (int)n;
  }
  __syncthreads();
  {
    int* px = pk0;
    int* py = pk1;
    for (int rd = 0; rd < 14; rd++) {
      for (int a = tid; a < NA; a += nt) {
        int cur_ = px[a];
        int n = cur_ & 0xFFFF;
        if (n != (int)NILA) {
          int o = px[n];
          cur_ = (((cur_ >> 16) + (o >> 16)) << 16) | (o & 0xFFFF);
        }
        py[a] = cur_;
      }
      __syncthreads();
      int* tp = px; px = py; py = tp;
    }
    // 14 rounds (even) -> result in pk0; extract ranks to r_a @102408 (succ dead)
    for (int a = tid; a < NA; a += nt) r_a[a] = (unsigned short)(pk0[a] >> 16);
  }
  __syncthreads();
  // ---- tour values + shfl scan -> H ----
  for (int a = tid; a < NA; a += nt) {
    int pa = NA - 1 - (int)r_a[a];
    int pb = NA - 1 - (int)r_a[a ^ 1];
    H[pa] = (pa < pb) ? (short)1 : (short)-1;
  }
  __syncthreads();
  {
    const int SCH = 13;
    int base = tid * SCH;
    int lim = base + SCH; if (lim > NA) lim = NA;
    int s = 0;
    for (int j = base; j < lim; j++) s += H[j];
    int run = blockScanEx(s);
    for (int j = base; j < lim; j++) { run += H[j]; H[j] = (short)run; }
  }
  __syncthreads();
  // ---- extract original-root depths + entry steps K ----
  if (tid == 0) { spackU = 0; smaxd = 0; scenter = 0x7FFFFFFF; }
  __syncthreads();
  for (int a = tid; a < NA; a += nt) {
    int pa = NA - 1 - (int)r_a[a];
    int pb = NA - 1 - (int)r_a[a ^ 1];
    if (pa < pb) {                       // down arc under ROOT rooting
      int e = a >> 1;
      int head = (a & 1) ? mu[e] : mv[e];
      depthR[head] = (unsigned short)H[pa];
      firstK[head] = (unsigned short)(pa + 1);
    }
  }
  if (tid == 0) { depthR[ROOT] = 0; firstK[ROOT] = 0; }
  __syncthreads();
  {
    int loc = 0;
    for (int v = tid; v < VV; v += nt) { int p = ((int)depthR[v] << 13) | v; if (p > loc) loc = p; }
    #pragma unroll
    for (int d = 32; d > 0; d >>= 1) { int o = __shfl_down(loc, d); if (o > loc) loc = o; }
    if (lane == 0) atomicMax(&spackU, loc);
  }
  __syncthreads();
  // ---- RMQ build: wave-parallel segmented min-scan ----
  {
    for (int seg = wid; seg < NB; seg += 16) {
      int p = seg * 64 + lane;
      int h = (p < NA) ? (int)H[p] : 32767;
      int hp = h;
      #pragma unroll
      for (int d = 1; d < 64; d <<= 1) { int o = __shfl_up(hp, d); if (lane >= d && o < hp) hp = o; }
      prefmin[p] = (short)hp;
      int hs = h;
      #pragma unroll
      for (int d = 1; d < 64; d <<= 1) { int o = __shfl_down(hs, d); if (lane + d < 64 && o < hs) hs = o; }
      sufmin[p] = (short)hs;
      if (lane == 0) tbl[seg] = (short)hs;
    }
  }
  __syncthreads();
  for (int k = 1; k < 8; k++) {
    short vv_ = 0;
    if (tid < NB) {
      int o = tid + (1 << (k - 1));
      short a = tbl[(k - 1) * NB + tid];
      short b2 = (o < NB) ? tbl[(k - 1) * NB + o] : (short)32767;
      vv_ = (a < b2) ? a : b2;
    }
    __syncthreads();
    if (tid < NB) tbl[k * NB + tid] = vv_;
    __syncthreads();
  }
  auto distq = [&](int K1, int K2) -> int {
    if (K1 == K2) return 0;
    int l = (K1 < K2 ? K1 : K2) - 1;
    int r = (K1 > K2 ? K1 : K2) - 1;
    int m = 32767;
    int l0 = l < 0 ? 0 : l;
    int bl = l0 >> 6, br = r >> 6;
    if (bl == br) {
      for (int p = l0; p <= r; p++) { int h = H[p]; if (h < m) m = h; }
    } else {
      int a = sufmin[l0], b2 = prefmin[r];
      m = a < b2 ? a : b2;
      int lo = bl + 1, hi = br - 1;
      if (lo <= hi) {
        int L = hi - lo + 1;
        int k = 31 - __builtin_clz(L);
        int c1 = tbl[k * NB + lo];
        int c2 = tbl[k * NB + hi - (1 << k) + 1];
        if (c1 < m) m = c1;
        if (c2 < m) m = c2;
      }
    }
    if (l < 0 && 0 < m) m = 0;
    int h1 = (K1 == 0) ? 0 : (int)H[K1 - 1];
    int h2 = (K2 == 0) ? 0 : (int)H[K2 - 1];
    return h1 + h2 - 2 * m;
  };
  int u = spackU & 0x1FFF;
  int Ku = firstK[u];
  if (tid == 0) spackW = 0;
  __syncthreads();
  {
    int loc = 0;
    for (int v = tid; v < VV; v += nt) {
      int d = distq(Ku, firstK[v]);
      distU[v] = (unsigned short)d;
      int p = (d << 13) | v;
      if (p > loc) loc = p;
    }
    #pragma unroll
    for (int d = 32; d > 0; d >>= 1) { int o = __shfl_down(loc, d); if (o > loc) loc = o; }
    if (lane == 0) atomicMax(&spackW, loc);
  }
  __syncthreads();
  int D = spackW >> 13;
  int w = spackW & 0x1FFF;
  int Kw = firstK[w];
  for (int v = tid; v < VV; v += nt) dbuf2[v] = (unsigned short)distq(Kw, firstK[v]);
  __syncthreads();
  {
    int half = D >> 1;
    for (int v = tid; v < VV; v += nt) {
      if ((int)distU[v] == half && (int)distU[v] + (int)dbuf2[v] == D) atomicMin(&scenter, v);
    }
  }
  __syncthreads();
  int cvert = (scenter == 0x7FFFFFFF) ? ROOT : scenter;
  int Kc = firstK[cvert];
  __syncthreads();
  {
    int loc = 0;
    for (int v = tid; v < VV; v += nt) {
      int d = distq(Kc, firstK[v]);
      dbuf2[v] = (unsigned short)d;
      if (d > loc) loc = d;
    }
    #pragma unroll
    for (int d = 32; d > 0; d >>= 1) { int o = __shfl_down(loc, d); if (o > loc) loc = o; }
    if (lane == 0) atomicMax(&smaxd, loc);
  }
  __syncthreads();
  int maxd = smaxd;
  int sTil = Kc;
  // ---- parents under c: one rotated arc-pass ----
  for (int a = tid; a < NA; a += nt) {
    int pa = NA - 1 - (int)r_a[a];
    int pb = NA - 1 - (int)r_a[a ^ 1];
    int pa2 = pa - sTil; if (pa2 < 0) pa2 += NA;
    int pb2 = pb - sTil; if (pb2 < 0) pb2 += NA;
    if (pa2 < pb2) {
      int e = a >> 1;
      int head = (a & 1) ? mu[e] : mv[e];
      int tail = (a & 1) ? mv[e] : mu[e];
      parentS[head] = (unsigned short)tail;
    }
  }
  if (tid == 0) parentS[cvert] = (unsigned short)cvert;
  __syncthreads();
  // ---- Phase D: counting sort by dist-from-center ----
  for (int d = tid; d <= VV; d += nt) lev[d] = 0;
  __syncthreads();
  for (int v = tid; v < VV; v += nt) atomicAdd(&lev[dbuf2[v]], 1);
  __syncthreads();
  {
    const int SCH = 7;
    int base = tid * SCH;
    int s = 0;
    #pragma unroll
    for (int k = 0; k < SCH; k++) { int d = base + k; if (d <= VV) s += lev[d]; }
    int ex = blockScanEx(s);
    #pragma unroll
    for (int k = 0; k < SCH; k++) {
      int d = base + k;
      if (d <= VV) {
        int st = ex;
        ex += lev[d];
        if (d < VV) cur[d] = st;
        lpG[t * (VV + 1) + d] = st;
      }
    }
  }
  __syncthreads();
  for (int v = tid; v < VV; v += nt) {
    int d = dbuf2[v];
    int slot = atomicAdd(&cur[d], 1);
    ordS[slot] = (unsigned short)v;
    posS[v] = (unsigned short)slot;
  }
  __syncthreads();
  for (int j = tid; j < VV; j += nt) {
    int v = ordS[j];
    int pv = parentS[v];
    ordG[t * VV + j] = v;
    pvG[t * VV + j] = pv;
    spG[t * VV + j] = posS[pv];
  }
  if (tid == 0) nlevG[t] = maxd + 1;
}

// ---------------- K5: per-position weight to parent (edge-key reuse; root -> 1, unused) ----------------
__global__ void k_weights(const unsigned long long* __restrict__ ekey,
                          const int* __restrict__ ordG, const int* __restrict__ pvG,
                          float* __restrict__ wvp) {
  int i = blockIdx.x * blockDim.x + threadIdx.x;
  if (i >= TT * VV) return;
  int t = i / VV;
  int v = ordG[i], p = pvG[i];
  float wout;
  if (v == p) {
    wout = 1.0f;  // root (overridden in filter transform)
  } else {
    int a = v < p ? v : p;
    int diff = v < p ? p - v : v - p;
    int e;
    if (diff == WW) e = a;
    else { int r = a / WW, c = a - r * WW; e = EVERT + r * (WW - 1) + c; }
    unsigned long long k = ekey[(size_t)t * EE + e];
    double cost = __longlong_as_double((long long)(k & ~0x3FFFULL));
    wout = expf(-(float)cost / SIGMA_F);
  }
  wvp[i] = wout;
}

// ---------------- K6: tree filter — level-sweep up (wave 0), packed-float2 doubling down ----------------
__global__ __launch_bounds__(512) void k_filter_pc(const float* __restrict__ Fsrc, float* __restrict__ Araw,
    const float* __restrict__ wvp, const int* __restrict__ ordG, const int* __restrict__ spG,
    const int* __restrict__ lpG, const int* __restrict__ nlevG, int treeBase) {
  int blk = blockIdx.x;
  int b = blk / CF, ch = blk - b * CF;
  int t = treeBase + b;
  __shared__ alignas(16) char arena[140816];
  float2* ab0 = (float2*)(arena);
  float2* ab1 = (float2*)(arena + 51200);
  float*  S   = (float*)(arena + 51200);
  float*  w   = (float*)(arena + 76800);
  unsigned short* sp0 = (unsigned short*)(arena + 102400);
  unsigned short* sp1 = (unsigned short*)(arena + 115200);
  unsigned short* lpS = (unsigned short*)(arena + 128000);
  const int* ord = ordG + t * VV;
  const int* spt = spG + t * VV;
  const float* wsrc = wvp + t * VV;
  const int* lp = lpG + t * (VV + 1);
  int tid = threadIdx.x;
  const int nt = 512;
  int NL = nlevG[t];
  for (int j = tid; j <= NL; j += nt) lpS[j] = (unsigned short)lp[j];
  const bool norm_in = (treeBase != 0);
  for (int j = tid; j < VV; j += nt) {
    sp0[j] = (unsigned short)spt[j];
    w[j] = wsrc[j];
    float val;
    if (ch < CP) {
      int v = ord[j];
      if (!norm_in) val = Fsrc[((size_t)b * CP + ch) * VV + v];
      else          val = Fsrc[((size_t)b * CF + ch) * VV + v] / Fsrc[((size_t)b * CF + CP) * VV + v];
    } else val = 1.0f;
    S[j] = val;
  }
  __syncthreads();
  if (tid < 64) {
    int s1 = lpS[NL];
    int s0 = lpS[NL - 1];
    for (int l = NL - 1; l >= 1; l--) {
      int s0n = (l > 1) ? (int)lpS[l - 1] : 0;
      for (int j = s0 + tid; j < s1; j += 64) {
        atomicAdd(&S[sp0[j]], w[j] * S[j]);
      }
      asm volatile("s_waitcnt lgkmcnt(0)" ::: "memory");
      __builtin_amdgcn_sched_barrier(0);
      s1 = s0; s0 = s0n;
    }
  }
  __syncthreads();
  for (int j = tid; j < VV; j += nt) {
    float wv = w[j];
    float a = (j == 0) ? 0.f : wv;
    float bv = (j == 0) ? S[0] : S[j] * (1.f - wv * wv);
    ab0[j] = make_float2(a, bv);
  }
  __syncthreads();
  int rounds = 0;
  { int d = 1; while (d < NL) { d <<= 1; rounds++; } }
  float2 *abs_ = ab0, *abd_ = ab1;
  unsigned short *ps_ = sp0, *pd_ = sp1;
  for (int r = 0; r < rounds; r++) {
    for (int j = tid; j < VV; j += nt) {
      float2 m = abs_[j];
      int p = ps_[j];
      float2 o = m;
      int pn = p;
      if (m.x != 0.f) {
        float2 mp = abs_[p];
        pn = ps_[p];
        o.x = m.x * mp.x;
        o.y = fmaf(m.x, mp.y, m.y);
      }
      abd_[j] = o;
      pd_[j] = (unsigned short)pn;
    }
    __syncthreads();
    float2* tf = abs_; abs_ = abd_; abd_ = tf;
    unsigned short* tu = ps_; ps_ = pd_; pd_ = tu;
  }
  float* Ob = Araw + ((size_t)b * CF + ch) * VV;
  for (int j = tid; j < VV; j += nt) Ob[ord[j]] = abs_[j].y;
}

// ---------------- K7: ROI-masked L1 loss (fused normalize of stage 2) ----------------
__global__ void k_loss(const float* __restrict__ prob, const float* __restrict__ Araw2,
                       const int* __restrict__ roi, double* __restrict__ acc) {
  int i = blockIdx.x * blockDim.x + threadIdx.x;
  int tid = threadIdx.x;
  double s = 0.0, n = 0.0;
  if (i < BB * VV) {
    int b = i / VV, v = i - b * VV;
    if (roi[i] != 0) {
      n = 1.0;
      const float* pb = prob + (size_t)b * CP * VV + v;
      const float* ab = Araw2 + (size_t)b * CF * VV + v;
      float inv = 1.0f / ab[CP * VV];
      float ls = 0.f;
      #pragma unroll
      for (int c = 0; c < CP; c++) ls += fabsf(pb[c * VV] - ab[c * VV] * inv);
      s = (double)ls;
    }
  }
  __shared__ double rs[256], rn[256];
  rs[tid] = s; rn[tid] = n;
  __syncthreads();
  for (int d = 128; d > 0; d >>= 1) {
    if (tid < d) { rs[tid] += rs[tid + d]; rn[tid] += rn[tid + d]; }
    __syncthreads();
  }
  if (tid == 0) { atomicAdd(&acc[0], rs[0]); atomicAdd(&acc[1], rn[0]); }
}

__global__ void k_finalize(const double* __restrict__ acc, float* __restrict__ out) {
  out[0] = (acc[1] > 0.0) ? (float)(acc[0] / acc[1]) : 0.0f;
}

extern "C" void kernel_launch(void* const* d_in, const int* in_sizes, int n_in,
                              void* d_out, int out_size, void* d_ws, size_t ws_size,
                              hipStream_t stream) {
  const float* preds = (const float*)d_in[0];
  const float* low   = (const float*)d_in[1];
  const float* high  = (const float*)d_in[2];
  const int*   roi   = (const int*)d_in[3];
  float* out = (float*)d_out;

  char* w = (char*)d_ws;
  size_t off = 0;
  auto alloc = [&](size_t bytes) -> void* {
    void* p = w + off;
    off += (bytes + 255) & ~(size_t)255;
    return p;
  };
  float* prob  = (float*)alloc((size_t)BB * CP * VV * 4);
  float* Araw1 = (float*)alloc((size_t)BB * CF * VV * 4);
  float* Araw2 = (float*)alloc((size_t)BB * CF * VV * 4);
  unsigned long long* ekey = (unsigned long long*)alloc((size_t)TT * EE * 8);
  int* mstU = (int*)alloc((size_t)TT * VV * 4);
  int* mstV = (int*)alloc((size_t)TT * VV * 4);
  int* ordG = (int*)alloc((size_t)TT * VV * 4);
  int* spG  = (int*)alloc((size_t)TT * VV * 4);
  int* pvG  = (int*)alloc((size_t)TT * VV * 4);
  int* lpG  = (int*)alloc((size_t)TT * (VV + 1) * 4);
  int* nlev = (int*)alloc((size_t)TT * 4);
  float* wvp = (float*)alloc((size_t)TT * VV * 4);
  double* acc = (double*)alloc(16);

  hipMemsetAsync(acc, 0, 16, stream);

  k_softmax<<<(BB * VV + 255) / 256, 256, 0, stream>>>(preds, prob);
  k_edgekey<<<(TT * EE + 255) / 256, 256, 0, stream>>>(low, high, ekey);
  k_boruvka<<<TT, 1024, 0, stream>>>(ekey, mstU, mstV);
  k_buildtree<<<TT, 1024, 0, stream>>>(mstU, mstV, ordG, spG, pvG, lpG, nlev);
  k_weights<<<(TT * VV + 255) / 256, 256, 0, stream>>>(ekey, ordG, pvG, wvp);
  k_filter_pc<<<BB * CF, 512, 0, stream>>>(prob,  Araw1, wvp, ordG, spG, lpG, nlev, 0);
  k_filter_pc<<<BB * CF, 512, 0, stream>>>(Araw1, Araw2, wvp, ordG, spG, lpG, nlev, BB);
  k_loss<<<(BB * VV + 255) / 256, 256, 0, stream>>>(prob, Araw2, roi, acc);
  k_finalize<<<1, 1, 0, stream>>>(acc, out);
}